// Round 15
// baseline (349.880 us; speedup 1.0000x reference)
//
#include <hip/hip_runtime.h>
#include <hip/hip_cooperative_groups.h>
#include <math.h>

#define D 256
#define H2 512
#define HEADS 8
#define L 25
#define GH 64
#define GW 64
#define NN 4096
#define EPS 1e-5f
#define SCALE 0.17677669529663687f  // 1/sqrt(32)
#define NND 1048576                 // NN*D

typedef __attribute__((ext_vector_type(8))) short short8;
typedef __attribute__((ext_vector_type(4))) short short4v;
typedef __attribute__((ext_vector_type(4))) float f32x4;

__device__ __forceinline__ bool act_at(const int* __restrict__ active, int h, int w) {
    if (h < 0 || h >= GH || w < 0 || w >= GW) return false;
    if (h == 2 && w == 2) return false;   // ap.at[:, center, center].set(False) quirk
    return active[h * GW + w] != 0;
}

__device__ __forceinline__ unsigned short f2b(float f) {
    unsigned u = __float_as_uint(f);
    u += 0x7fffu + ((u >> 16) & 1u);      // RNE
    return (unsigned short)(u >> 16);
}
__device__ __forceinline__ float b2f(short v) {
    return __uint_as_float(((unsigned)(unsigned short)v) << 16);
}

__device__ __forceinline__ void dma16(const unsigned short* g, unsigned short* l) {
    __builtin_amdgcn_global_load_lds(
        (const __attribute__((address_space(1))) unsigned int*)g,
        (__attribute__((address_space(3))) unsigned int*)l, 16, 0, 0);
}

// ---------------- dynamic LDS layout (138240 B) ----------------
#define BK_OFF   0            // K union: 100 x 256 bf16 = 51200 (phase W: f32 tile 64x65)
#define BV_OFF   51200        // V union: 51200
#define T1B_OFF  102400       // [16][264] bf16 = 8448
#define SB_OFF   110848       // [16][264] bf16 = 8448
#define HB_OFF   119296       // [16][520] bf16 = 16640
#define ACT_OFF  135936       // 128
#define REDA_OFF 136064       // [16][16] f32 = 1024
#define REDB_OFF 137088       // 1024
#define STAT_OFF 138112       // 128
#define SMEM_SZ  138240

__device__ __forceinline__ int union_row(int c, int h, int w0, int fallback) {
    int u = c >> 5;
    int r = u / 20;
    int hh = h - 2 + r, ww = w0 - 2 + (u - r * 20);
    bool ib = ((unsigned)hh < GH) && ((unsigned)ww < GW);
    return ib ? ((hh << 6) | ww) : fallback;
}

__device__ __forceinline__ void dma_union(const unsigned short* __restrict__ base,
                                          int h, int w0, int fallback,
                                          unsigned short* dstLds, int tid) {
    #pragma unroll
    for (int k = 0; k < 4; ++k) {
        int c = tid + k * 1024;
        if (c < 3200) {
            int row = union_row(c, h, w0, fallback);
            dma16(base + (size_t)row * 256 + (c & 31) * 8, dstLds + (size_t)c * 8);
        }
    }
}

// ---------------- mega kernel: prep + proj + fused chain, cooperative ----------------
__global__ __launch_bounds__(1024)
void mega_kernel(const int* __restrict__ active, const float* __restrict__ x,
                 const float* __restrict__ memf,
                 const float* __restrict__ attn_w, const float* __restrict__ attn_b,
                 const float* __restrict__ pattn_w, const float* __restrict__ pattn_b,
                 const float* __restrict__ ff_w1, const float* __restrict__ ff_b1,
                 const float* __restrict__ ff_w2, const float* __restrict__ ff_b2,
                 const float* __restrict__ ln_g, const float* __restrict__ ln_b,
                 unsigned short* __restrict__ xmB, unsigned short* __restrict__ memB,
                 unsigned short* __restrict__ wB,
                 unsigned short* __restrict__ q1b, unsigned short* __restrict__ k1b,
                 unsigned short* __restrict__ v1b, unsigned short* __restrict__ k2b,
                 unsigned short* __restrict__ v2b,
                 float* __restrict__ out) {
    extern __shared__ __align__(16) char smem[];
    unsigned short (*bufK)[256] = (unsigned short(*)[256])(smem + BK_OFF);
    unsigned short (*bufV)[256] = (unsigned short(*)[256])(smem + BV_OFF);
    unsigned short (*T1b)[264]  = (unsigned short(*)[264])(smem + T1B_OFF);
    unsigned short (*Sb)[264]   = (unsigned short(*)[264])(smem + SB_OFF);
    unsigned short (*Hb)[520]   = (unsigned short(*)[520])(smem + HB_OFF);
    unsigned char* actU         = (unsigned char*)(smem + ACT_OFF);
    float (*redA)[16]           = (float(*)[16])(smem + REDA_OFF);
    float (*redB)[16]           = (float(*)[16])(smem + REDB_OFF);
    float (*stats)[2]           = (float(*)[2])(smem + STAT_OFF);

    const int tid = threadIdx.x;              // 1024 threads, 16 waves
    const int wv = tid >> 6, lane = tid & 63;
    const int lr = lane & 15, qi = lane >> 4;
    const int m = wv;
    const int braw = blockIdx.x;
    const int bid = ((braw & 7) << 5) | (braw >> 3);   // XCD-chunked
    const int n0 = bid * 16;
    const int h = n0 >> 6, w0 = n0 & 63;

    // ================= Phase W: weight transpose + x/mem bf16 conversion ==========
    {
        // own-rows x/mem conversion (16 rows = 1024 float4 each)
        {
            const float4* xs = (const float4*)(x + (size_t)n0 * D);
            const float4* ms = (const float4*)(memf + (size_t)n0 * D);
            int rowLoc = tid >> 6;             // 16 rows, one per wave
            int n = n0 + rowLoc;
            bool a = act_at(active, n >> 6, n & 63);
            float4 v = xs[tid];
            ushort4 u;
            u.x = f2b(a ? v.x : 0.0f); u.y = f2b(a ? v.y : 0.0f);
            u.z = f2b(a ? v.z : 0.0f); u.w = f2b(a ? v.w : 0.0f);
            ((ushort4*)(xmB + (size_t)n0 * D))[tid] = u;
            float4 mv = ms[tid];
            ushort4 mu;
            mu.x = f2b(mv.x); mu.y = f2b(mv.y); mu.z = f2b(mv.z); mu.w = f2b(mv.w);
            ((ushort4*)(memB + (size_t)n0 * D))[tid] = mu;
        }
        // weight transpose tiles: 192 jobs on raw block id
        if (braw < 192) {
            float (*tile)[65] = (float(*)[65])(smem);   // 16.6 KB, aliases bufK
            const float* src; unsigned short* dst;
            int i0, nn0, srcLen, dstLen;
            if (braw < 128) {
                int mat = braw >> 4, t16 = braw & 15;
                i0 = (t16 >> 2) * 64; nn0 = (t16 & 3) * 64;
                src = (mat < 4) ? (attn_w + mat * 65536) : (pattn_w + (mat - 4) * 65536);
                dst = wB + mat * 65536;
                srcLen = 256; dstLen = 256;
            } else if (braw < 160) {
                int t = braw - 128;
                i0 = (t >> 3) * 64; nn0 = (t & 7) * 64;
                src = ff_w1; dst = wB + 524288;      // W1T: [512][256]
                srcLen = 512; dstLen = 256;
            } else {
                int t = braw - 160;
                i0 = (t >> 2) * 64; nn0 = (t & 3) * 64;
                src = ff_w2; dst = wB + 655360;      // W2T: [256][512]
                srcLen = 256; dstLen = 512;
            }
            int c = tid & 63, r16 = tid >> 6;
            #pragma unroll
            for (int rr = 0; rr < 64; rr += 16)
                tile[rr + r16][c] = src[(size_t)(i0 + rr + r16) * srcLen + nn0 + c];
            __syncthreads();
            #pragma unroll
            for (int rr = 0; rr < 64; rr += 16) {
                int r = rr + r16;
                dst[(size_t)(nn0 + r) * dstLen + i0 + c] = f2b(tile[c][r]);
            }
        }
        if (braw == 255 && tid < 512) {
            if (tid < 256) k2b[(size_t)NND + tid] = f2b(pattn_b[256 + tid]);
            else           v2b[(size_t)NND + (tid - 256)] = f2b(pattn_b[512 + (tid - 256)]);
        }
    }
    __threadfence();
    cooperative_groups::this_grid().sync();

    // ================= Phase P: proj for own 16 rows (5 streams) ==================
    {
        #pragma unroll
        for (int i = 0; i < 5; ++i) {
            const unsigned short* A = (i < 3) ? (xmB + (size_t)n0 * D)
                                              : (memB + (size_t)n0 * D);
            int wtIdx = (i < 3) ? i : (i + 2);
            const unsigned short* WT = wB + (size_t)wtIdx * 65536;
            const float* bias = (i < 3) ? (attn_b + i * 256) : (pattn_b + (i - 2) * 256);
            unsigned short* outB;
            switch (i) { case 0: outB = q1b; break; case 1: outB = k1b; break;
                         case 2: outB = v1b; break; case 3: outB = k2b; break;
                         default: outB = v2b; }
            f32x4 acc = {};
            const unsigned short* arow = A  + (size_t)lr * 256 + qi * 8;
            const unsigned short* brow = WT + (size_t)(wv * 16 + lr) * 256 + qi * 8;
            #pragma unroll
            for (int kk = 0; kk < 256; kk += 32) {
                short8 a = *(const short8*)(arow + kk);
                short8 b = *(const short8*)(brow + kk);
                acc = __builtin_amdgcn_mfma_f32_16x16x32_bf16(a, b, acc, 0, 0, 0);
            }
            const int c = wv * 16 + lr;
            float bc = bias[c];
            #pragma unroll
            for (int jj = 0; jj < 4; ++jj)
                outB[(size_t)(n0 + qi * 4 + jj) * 256 + c] = f2b(acc[jj] + bc);
        }
    }
    __threadfence();
    cooperative_groups::this_grid().sync();

    // ================= Phase F: fused attention chain (R14 body) ==================
    // ---- P0: masks + K1/V1 unions via async DMA ----
    dma_union(k1b, h, w0, 0, (unsigned short*)(smem + BK_OFF), tid);
    dma_union(v1b, h, w0, 0, (unsigned short*)(smem + BV_OFF), tid);
    if (tid < 100) {
        int r = tid / 20;
        int hh = h - 2 + r, ww = w0 - 2 + (tid - r * 20);
        actU[tid] = act_at(active, hh, ww) ? 1 : 0;
    }
    __syncthreads();

    // ---- A1: scores + in-register softmax + PV ----
    {
        float q[4];
        {
            short4v qv = *(const short4v*)(q1b + (size_t)(n0 + m) * 256 + lane * 4);
            #pragma unroll
            for (int j = 0; j < 4; ++j) q[j] = b2f(qv[j]);
        }
        float sc[L];
        #pragma unroll
        for (int l = 0; l < L; ++l) {
            int u = (l / 5) * 20 + m + (l % 5);
            short4v kv = *(const short4v*)&bufK[u][lane * 4];
            float p = q[0] * b2f(kv[0]);
            #pragma unroll
            for (int j = 1; j < 4; ++j) p = fmaf(q[j], b2f(kv[j]), p);
            p += __shfl_xor(p, 1); p += __shfl_xor(p, 2); p += __shfl_xor(p, 4);
            sc[l] = actU[u] ? p * SCALE : -1e30f;
        }
        float mx = sc[0];
        #pragma unroll
        for (int l = 1; l < L; ++l) mx = fmaxf(mx, sc[l]);
        float sum = 0.0f;
        #pragma unroll
        for (int l = 0; l < L; ++l) { sc[l] = expf(sc[l] - mx); sum += sc[l]; }
        float inv = 1.0f / sum;
        float o[4] = {0.f, 0.f, 0.f, 0.f};
        #pragma unroll
        for (int l = 0; l < L; ++l) {
            int u = (l / 5) * 20 + m + (l % 5);
            short4v v4 = *(const short4v*)&bufV[u][lane * 4];
            #pragma unroll
            for (int j = 0; j < 4; ++j) o[j] = fmaf(sc[l], b2f(v4[j]), o[j]);
        }
        unsigned short u8[4];
        #pragma unroll
        for (int j = 0; j < 4; ++j) u8[j] = f2b(o[j] * inv);
        *(uint2*)&T1b[m][lane * 4] = *(uint2*)u8;
    }
    __syncthreads();

    // ---- P4: issue K2/V2 DMA; Wo1 + bias + resid(x) + LN0 -> sreg + Sb ----
    float sreg[4];
    {
        dma_union(k2b, h, w0, NN, (unsigned short*)(smem + BK_OFF), tid);
        dma_union(v2b, h, w0, NN, (unsigned short*)(smem + BV_OFF), tid);
        const unsigned short* Wo1T = wB + 3 * 65536;
        f32x4 acc = {};
        #pragma unroll
        for (int kk = 0; kk < 256; kk += 32) {
            short8 a = *(const short8*)&T1b[lr][qi * 8 + kk];
            short8 b = *(const short8*)(Wo1T + (size_t)(wv * 16 + lr) * 256 + qi * 8 + kk);
            acc = __builtin_amdgcn_mfma_f32_16x16x32_bf16(a, b, acc, 0, 0, 0);
        }
        const int c = wv * 16 + lr;
        float bc = attn_b[768 + c];
        float v[4], s1[4], s2[4];
        #pragma unroll
        for (int jj = 0; jj < 4; ++jj) {
            int row = n0 + qi * 4 + jj;
            float vv = acc[jj] + bc + x[(size_t)row * D + c];
            v[jj] = vv; s1[jj] = vv; s2[jj] = vv * vv;
        }
        #pragma unroll
        for (int jj = 0; jj < 4; ++jj) {
            #pragma unroll
            for (int off = 1; off < 16; off <<= 1) {
                s1[jj] += __shfl_xor(s1[jj], off);
                s2[jj] += __shfl_xor(s2[jj], off);
            }
        }
        if (lr == 0) {
            #pragma unroll
            for (int jj = 0; jj < 4; ++jj) { redA[qi*4+jj][wv] = s1[jj]; redB[qi*4+jj][wv] = s2[jj]; }
        }
        __syncthreads();
        if (tid < 16) {
            float a1 = 0.f, a2 = 0.f;
            #pragma unroll
            for (int q8 = 0; q8 < 16; ++q8) { a1 += redA[tid][q8]; a2 += redB[tid][q8]; }
            float mu = a1 * (1.0f / D);
            float var = a2 * (1.0f / D) - mu * mu;
            stats[tid][0] = mu; stats[tid][1] = rsqrtf(var + EPS);
        }
        __syncthreads();
        float gg = ln_g[c], bb = ln_b[c];
        #pragma unroll
        for (int jj = 0; jj < 4; ++jj) {
            int ridx = qi * 4 + jj;
            float ov = (v[jj] - stats[ridx][0]) * stats[ridx][1] * gg + bb;
            sreg[jj] = ov;
            Sb[ridx][c] = f2b(ov);
        }
    }
    __syncthreads();

    // ---- P5: Wq2 (Sb) -> T1b -> q2 regs ----
    float q2[4];
    {
        const unsigned short* Wq2T = wB + 4 * 65536;
        f32x4 acc = {};
        #pragma unroll
        for (int kk = 0; kk < 256; kk += 32) {
            short8 a = *(const short8*)&Sb[lr][qi * 8 + kk];
            short8 b = *(const short8*)(Wq2T + (size_t)(wv * 16 + lr) * 256 + qi * 8 + kk);
            acc = __builtin_amdgcn_mfma_f32_16x16x32_bf16(a, b, acc, 0, 0, 0);
        }
        const int c = wv * 16 + lr;
        float bc = pattn_b[c];
        #pragma unroll
        for (int jj = 0; jj < 4; ++jj)
            T1b[qi * 4 + jj][c] = f2b(acc[jj] + bc);
        __syncthreads();
        short4v qv = *(const short4v*)&T1b[m][lane * 4];
        #pragma unroll
        for (int j = 0; j < 4; ++j) q2[j] = b2f(qv[j]);
    }

    // ---- A2: scores + in-register softmax + PV (bufK=K2, bufV=V2) ----
    {
        float sc[L];
        #pragma unroll
        for (int l = 0; l < L; ++l) {
            int u = (l / 5) * 20 + m + (l % 5);
            short4v kv = *(const short4v*)&bufK[u][lane * 4];
            float p = q2[0] * b2f(kv[0]);
            #pragma unroll
            for (int j = 1; j < 4; ++j) p = fmaf(q2[j], b2f(kv[j]), p);
            p += __shfl_xor(p, 1); p += __shfl_xor(p, 2); p += __shfl_xor(p, 4);
            sc[l] = p * SCALE;
        }
        float mx = sc[0];
        #pragma unroll
        for (int l = 1; l < L; ++l) mx = fmaxf(mx, sc[l]);
        float sum = 0.0f;
        #pragma unroll
        for (int l = 0; l < L; ++l) { sc[l] = expf(sc[l] - mx); sum += sc[l]; }
        float inv = 1.0f / sum;
        float o[4] = {0.f, 0.f, 0.f, 0.f};
        #pragma unroll
        for (int l = 0; l < L; ++l) {
            int u = (l / 5) * 20 + m + (l % 5);
            short4v v4 = *(const short4v*)&bufV[u][lane * 4];
            #pragma unroll
            for (int j = 0; j < 4; ++j) o[j] = fmaf(sc[l], b2f(v4[j]), o[j]);
        }
        unsigned short u8[4];
        #pragma unroll
        for (int j = 0; j < 4; ++j) u8[j] = f2b(o[j] * inv);
        *(uint2*)&T1b[m][lane * 4] = *(uint2*)u8;
    }
    __syncthreads();

    // ---- P8: Wo2 + bias + resid(sreg) + LN2 -> s2reg + Sb ----
    float s2reg[4];
    {
        const unsigned short* Wo2T = wB + 7 * 65536;
        f32x4 acc = {};
        #pragma unroll
        for (int kk = 0; kk < 256; kk += 32) {
            short8 a = *(const short8*)&T1b[lr][qi * 8 + kk];
            short8 b = *(const short8*)(Wo2T + (size_t)(wv * 16 + lr) * 256 + qi * 8 + kk);
            acc = __builtin_amdgcn_mfma_f32_16x16x32_bf16(a, b, acc, 0, 0, 0);
        }
        const int c = wv * 16 + lr;
        float bc = pattn_b[768 + c];
        float v[4], s1[4], s2[4];
        #pragma unroll
        for (int jj = 0; jj < 4; ++jj) {
            float vv = acc[jj] + bc + sreg[jj];
            v[jj] = vv; s1[jj] = vv; s2[jj] = vv * vv;
        }
        #pragma unroll
        for (int jj = 0; jj < 4; ++jj) {
            #pragma unroll
            for (int off = 1; off < 16; off <<= 1) {
                s1[jj] += __shfl_xor(s1[jj], off);
                s2[jj] += __shfl_xor(s2[jj], off);
            }
        }
        if (lr == 0) {
            #pragma unroll
            for (int jj = 0; jj < 4; ++jj) { redA[qi*4+jj][wv] = s1[jj]; redB[qi*4+jj][wv] = s2[jj]; }
        }
        __syncthreads();
        if (tid < 16) {
            float a1 = 0.f, a2 = 0.f;
            #pragma unroll
            for (int q8 = 0; q8 < 16; ++q8) { a1 += redA[tid][q8]; a2 += redB[tid][q8]; }
            float mu = a1 * (1.0f / D);
            float var = a2 * (1.0f / D) - mu * mu;
            stats[tid][0] = mu; stats[tid][1] = rsqrtf(var + EPS);
        }
        __syncthreads();
        float gg = ln_g[512 + c], bb = ln_b[512 + c];
        #pragma unroll
        for (int jj = 0; jj < 4; ++jj) {
            int ridx = qi * 4 + jj;
            float ov = (v[jj] - stats[ridx][0]) * stats[ridx][1] * gg + bb;
            s2reg[jj] = ov;
            Sb[ridx][c] = f2b(ov);
        }
    }
    __syncthreads();

    // ---- P9: FF1 (Sb = S2) -> Hb ----
    {
        const unsigned short* W1T = wB + 524288;
        f32x4 acc[2] = {};
        #pragma unroll
        for (int kk = 0; kk < 256; kk += 32) {
            short8 a = *(const short8*)&Sb[lr][qi * 8 + kk];
            #pragma unroll
            for (int nf = 0; nf < 2; ++nf) {
                short8 b = *(const short8*)(W1T + (size_t)(wv * 32 + nf * 16 + lr) * 256 + qi * 8 + kk);
                acc[nf] = __builtin_amdgcn_mfma_f32_16x16x32_bf16(a, b, acc[nf], 0, 0, 0);
            }
        }
        #pragma unroll
        for (int nf = 0; nf < 2; ++nf) {
            int c = wv * 32 + nf * 16 + lr;
            float bc = ff_b1[c];
            #pragma unroll
            for (int jj = 0; jj < 4; ++jj)
                Hb[qi * 4 + jj][c] = f2b(fmaxf(acc[nf][jj] + bc, 0.0f));
        }
    }
    __syncthreads();

    // ---- P10: FF2 (K=512) + resid(s2reg) + LN1 + mask -> out ----
    {
        const unsigned short* W2T = wB + 655360;
        f32x4 acc = {};
        #pragma unroll
        for (int kk = 0; kk < 512; kk += 32) {
            short8 a = *(const short8*)&Hb[lr][qi * 8 + kk];
            short8 b = *(const short8*)(W2T + (size_t)(wv * 16 + lr) * 512 + qi * 8 + kk);
            acc = __builtin_amdgcn_mfma_f32_16x16x32_bf16(a, b, acc, 0, 0, 0);
        }
        const int c = wv * 16 + lr;
        float bc = ff_b2[c];
        float v[4], s1[4], s2[4];
        #pragma unroll
        for (int jj = 0; jj < 4; ++jj) {
            float vv = acc[jj] + bc + s2reg[jj];
            v[jj] = vv; s1[jj] = vv; s2[jj] = vv * vv;
        }
        #pragma unroll
        for (int jj = 0; jj < 4; ++jj) {
            #pragma unroll
            for (int off = 1; off < 16; off <<= 1) {
                s1[jj] += __shfl_xor(s1[jj], off);
                s2[jj] += __shfl_xor(s2[jj], off);
            }
        }
        if (lr == 0) {
            #pragma unroll
            for (int jj = 0; jj < 4; ++jj) { redA[qi*4+jj][wv] = s1[jj]; redB[qi*4+jj][wv] = s2[jj]; }
        }
        __syncthreads();
        if (tid < 16) {
            float a1 = 0.f, a2 = 0.f;
            #pragma unroll
            for (int q8 = 0; q8 < 16; ++q8) { a1 += redA[tid][q8]; a2 += redB[tid][q8]; }
            float mu = a1 * (1.0f / D);
            float var = a2 * (1.0f / D) - mu * mu;
            stats[tid][0] = mu; stats[tid][1] = rsqrtf(var + EPS);
        }
        __syncthreads();
        bool arow_act[4];
        #pragma unroll
        for (int jj = 0; jj < 4; ++jj) {
            int row = n0 + qi * 4 + jj;
            arow_act[jj] = act_at(active, row >> 6, row & 63);
        }
        float gg = ln_g[256 + c], bb = ln_b[256 + c];
        #pragma unroll
        for (int jj = 0; jj < 4; ++jj) {
            int ridx = qi * 4 + jj;
            float ov = (v[jj] - stats[ridx][0]) * stats[ridx][1] * gg + bb;
            out[(size_t)(n0 + ridx) * D + c] = arow_act[jj] ? ov : 0.0f;
        }
        if (tid < 16) {
            int row = n0 + tid;
            out[(size_t)NND + row] = act_at(active, row >> 6, row & 63) ? 1.0f : 0.0f;
        }
    }
}

extern "C" void kernel_launch(void* const* d_in, const int* in_sizes, int n_in,
                              void* d_out, int out_size, void* d_ws, size_t ws_size,
                              hipStream_t stream) {
    const float* x       = (const float*)d_in[0];
    const float* memory  = (const float*)d_in[1];
    const int*   active  = (const int*)d_in[2];
    const float* attn_w  = (const float*)d_in[3];
    const float* attn_b  = (const float*)d_in[4];
    const float* pattn_w = (const float*)d_in[5];
    const float* pattn_b = (const float*)d_in[6];
    const float* ff_w1   = (const float*)d_in[7];
    const float* ff_b1   = (const float*)d_in[8];
    const float* ff_w2   = (const float*)d_in[9];
    const float* ff_b2   = (const float*)d_in[10];
    const float* ln_g    = (const float*)d_in[11];
    const float* ln_b    = (const float*)d_in[12];
    float* out = (float*)d_out;

    unsigned short* wsb = (unsigned short*)d_ws;
    unsigned short* xmB  = wsb;
    unsigned short* memB = wsb + (size_t)NND;
    unsigned short* wB   = wsb + 2 * (size_t)NND;               // 786432 shorts
    unsigned short* q1b  = wB + 786432;
    unsigned short* k1b  = q1b + (size_t)NND;
    unsigned short* v1b  = k1b + (size_t)NND;
    unsigned short* k2b  = v1b + (size_t)NND;                   // 4097 rows
    unsigned short* v2b  = k2b + (size_t)NND + 256;             // 4097 rows

    hipFuncSetAttribute(reinterpret_cast<const void*>(mega_kernel),
                        hipFuncAttributeMaxDynamicSharedMemorySize, SMEM_SZ);

    void* args[] = {
        (void*)&active, (void*)&x, (void*)&memory,
        (void*)&attn_w, (void*)&attn_b, (void*)&pattn_w, (void*)&pattn_b,
        (void*)&ff_w1, (void*)&ff_b1, (void*)&ff_w2, (void*)&ff_b2,
        (void*)&ln_g, (void*)&ln_b,
        (void*)&xmB, (void*)&memB, (void*)&wB,
        (void*)&q1b, (void*)&k1b, (void*)&v1b, (void*)&k2b, (void*)&v2b,
        (void*)&out
    };
    hipLaunchCooperativeKernel(reinterpret_cast<const void*>(mega_kernel),
                               dim3(256), dim3(1024), args, SMEM_SZ, stream);
}

// Round 16
// 85.155 us; speedup vs baseline: 4.1087x; 4.1087x over previous
//
#include <hip/hip_runtime.h>
#include <math.h>

#define D 256
#define H2 512
#define HEADS 8
#define L 25
#define GH 64
#define GW 64
#define NN 4096
#define EPS 1e-5f
#define SCALE 0.17677669529663687f  // 1/sqrt(32)
#define NND 1048576                 // NN*D

typedef __attribute__((ext_vector_type(8))) short short8;
typedef __attribute__((ext_vector_type(4))) short short4v;
typedef __attribute__((ext_vector_type(4))) float f32x4;

__device__ __forceinline__ bool act_at(const int* __restrict__ active, int h, int w) {
    if (h < 0 || h >= GH || w < 0 || w >= GW) return false;
    if (h == 2 && w == 2) return false;   // ap.at[:, center, center].set(False) quirk
    return active[h * GW + w] != 0;
}

__device__ __forceinline__ unsigned short f2b(float f) {
    unsigned u = __float_as_uint(f);
    u += 0x7fffu + ((u >> 16) & 1u);      // RNE
    return (unsigned short)(u >> 16);
}
__device__ __forceinline__ float b2f(short v) {
    return __uint_as_float(((unsigned)(unsigned short)v) << 16);
}

// async global->LDS DMA, 16 B per lane; lds dest = wave-uniform base + lane*16
__device__ __forceinline__ void dma16(const unsigned short* g, unsigned short* l) {
    __builtin_amdgcn_global_load_lds(
        (const __attribute__((address_space(1))) unsigned int*)g,
        (__attribute__((address_space(3))) unsigned int*)l, 16, 0, 0);
}

// ---------------- prep: bf16 conversions + LDS-tiled weight transposes ----------------
__global__ __launch_bounds__(256)
void prep_kernel(const float* __restrict__ x, const float* __restrict__ mem,
                 const int* __restrict__ active,
                 const float* __restrict__ attn_w, const float* __restrict__ pattn_w,
                 const float* __restrict__ ff_w1, const float* __restrict__ ff_w2,
                 const float* __restrict__ pattn_b,
                 unsigned short* __restrict__ xmB, unsigned short* __restrict__ memB,
                 unsigned short* __restrict__ wB,
                 unsigned short* __restrict__ k2bias, unsigned short* __restrict__ v2bias) {
    const int tid = threadIdx.x;
    const int bid = blockIdx.x;
    if (bid < 192) {
        __shared__ float tile[64][65];
        const float* src; unsigned short* dst;
        int i0, n0, srcLen, dstLen;
        if (bid < 128) {
            int mat = bid >> 4, t16 = bid & 15;
            i0 = (t16 >> 2) * 64; n0 = (t16 & 3) * 64;
            src = (mat < 4) ? (attn_w + mat * 65536) : (pattn_w + (mat - 4) * 65536);
            dst = wB + mat * 65536;
            srcLen = 256; dstLen = 256;
        } else if (bid < 160) {
            int t = bid - 128;
            i0 = (t >> 3) * 64; n0 = (t & 7) * 64;
            src = ff_w1; dst = wB + 524288;      // W1T: [512][256]
            srcLen = 512; dstLen = 256;
        } else {
            int t = bid - 160;
            i0 = (t >> 2) * 64; n0 = (t & 3) * 64;
            src = ff_w2; dst = wB + 655360;      // W2T: [256][512]
            srcLen = 256; dstLen = 512;
        }
        int c = tid & 63, r4 = tid >> 6;
        for (int rr = 0; rr < 64; rr += 4)
            tile[rr + r4][c] = src[(size_t)(i0 + rr + r4) * srcLen + n0 + c];
        __syncthreads();
        for (int rr = 0; rr < 64; rr += 4) {
            int r = rr + r4;
            dst[(size_t)(n0 + r) * dstLen + i0 + c] = f2b(tile[c][r]);
        }
    } else {
        const int t0 = (bid - 192) * 256 + tid;
        for (int t = t0; t < 524800; t += 512 * 256) {
            if (t < 262144) {
                int n = t >> 6;
                bool a = act_at(active, n >> 6, n & 63);
                float4 v = ((const float4*)x)[t];
                ushort4 u;
                u.x = f2b(a ? v.x : 0.0f); u.y = f2b(a ? v.y : 0.0f);
                u.z = f2b(a ? v.z : 0.0f); u.w = f2b(a ? v.w : 0.0f);
                ((ushort4*)xmB)[t] = u;
            } else if (t < 524288) {
                int tt = t - 262144;
                float4 v = ((const float4*)mem)[tt];
                ushort4 u;
                u.x = f2b(v.x); u.y = f2b(v.y); u.z = f2b(v.z); u.w = f2b(v.w);
                ((ushort4*)memB)[tt] = u;
            } else {
                int tt = t - 524288;
                if (tt < 256) k2bias[tt] = f2b(pattn_b[256 + tt]);
                else          v2bias[tt - 256] = f2b(pattn_b[512 + (tt - 256)]);
            }
        }
    }
}

// ---------------- proj: 5 GEMM streams -> bf16 outputs (XCD-aligned rows) ----------------
__global__ __launch_bounds__(256)
void proj_gemm(const unsigned short* __restrict__ xmB,
               const unsigned short* __restrict__ memB,
               const unsigned short* __restrict__ wB,
               const float* __restrict__ attn_b, const float* __restrict__ pattn_b,
               unsigned short* __restrict__ q1b, unsigned short* __restrict__ k1b,
               unsigned short* __restrict__ v1b, unsigned short* __restrict__ k2b,
               unsigned short* __restrict__ v2b) {
    const int s  = blockIdx.y >> 2;       // 0:Q1 1:K1 2:V1 3:K2 4:V2
    const int n0 = (blockIdx.y & 3) * 64;
    const unsigned short* A  = (s < 3) ? xmB : memB;
    const int wtIdx = (s < 3) ? s : (s + 2);            // K2->5, V2->6
    const unsigned short* WT = wB + (size_t)wtIdx * 65536;
    const float* bias = (s < 3) ? (attn_b + s * 256) : (pattn_b + (s - 2) * 256);
    unsigned short* outB;
    switch (s) { case 0: outB = q1b; break; case 1: outB = k1b; break;
                 case 2: outB = v1b; break; case 3: outB = k2b; break;
                 default: outB = v2b; }

    const int tid = threadIdx.x;
    const int wave = tid >> 6, lane = tid & 63;
    // XCD-aligned: hardware XCD = blockIdx.x & 7 (x-major dispatch, 64 % 8 == 0);
    // map so XCD k produces rows [k*512, k*512+512) — matches fused kernel's swizzle.
    const int xb = ((blockIdx.x & 7) << 3) | (blockIdx.x >> 3);
    const int m0 = xb * 64 + wave * 16;
    const int lr = lane & 15;
    const int lk = (lane >> 4) << 3;
    f32x4 acc[4] = {};
    const unsigned short* arow = A  + (size_t)(m0 + lr) * 256 + lk;
    const unsigned short* brow = WT + (size_t)(n0 + lr) * 256 + lk;
    #pragma unroll
    for (int kk = 0; kk < 256; kk += 32) {
        short8 a = *(const short8*)(arow + kk);
        #pragma unroll
        for (int nf = 0; nf < 4; ++nf) {
            short8 b = *(const short8*)(brow + (size_t)nf * 16 * 256 + kk);
            acc[nf] = __builtin_amdgcn_mfma_f32_16x16x32_bf16(a, b, acc[nf], 0, 0, 0);
        }
    }
    const int rbase = m0 + ((lane >> 4) << 2);
    #pragma unroll
    for (int nf = 0; nf < 4; ++nf) {
        int c = n0 + nf * 16 + lr;
        float bc = bias[c];
        #pragma unroll
        for (int jj = 0; jj < 4; ++jj)
            outB[(size_t)(rbase + jj) * 256 + c] = f2b(acc[nf][jj] + bc);
    }
}

// ---------------- dynamic LDS layout (138240 B) ----------------
#define BK_OFF   0            // K union: 100 x 256 bf16 = 51200
#define BV_OFF   51200        // V union: 51200
#define T1B_OFF  102400       // [16][264] bf16 = 8448
#define SB_OFF   110848       // [16][264] bf16 = 8448
#define HB_OFF   119296       // [16][520] bf16 = 16640
#define ACT_OFF  135936       // 128
#define REDA_OFF 136064       // [16][16] f32 = 1024
#define REDB_OFF 137088       // 1024
#define STAT_OFF 138112       // 128
#define SMEM_SZ  138240

__device__ __forceinline__ int union_row(int c, int h, int w0, int fallback) {
    int u = c >> 5;
    int r = u / 20;
    int hh = h - 2 + r, ww = w0 - 2 + (u - r * 20);
    bool ib = ((unsigned)hh < GH) && ((unsigned)ww < GW);
    return ib ? ((hh << 6) | ww) : fallback;
}

// 3200 chunks over 1024 threads: k<4, tail (k=3) = 2 full waves
__device__ __forceinline__ void dma_union(const unsigned short* __restrict__ base,
                                          int h, int w0, int fallback,
                                          unsigned short* dstLds, int tid) {
    #pragma unroll
    for (int k = 0; k < 4; ++k) {
        int c = tid + k * 1024;
        if (c < 3200) {
            int row = union_row(c, h, w0, fallback);
            dma16(base + (size_t)row * 256 + (c & 31) * 8, dstLds + (size_t)c * 8);
        }
    }
}

// ---------------- fused chain kernel: 1024 threads, 16 waves ----------------
__global__ __launch_bounds__(1024)
void fused_kernel(const int* __restrict__ active, const float* __restrict__ x,
                  const unsigned short* __restrict__ wB,
                  const float* __restrict__ attn_b, const float* __restrict__ pattn_b,
                  const float* __restrict__ ff_b1, const float* __restrict__ ff_b2,
                  const float* __restrict__ ln_g, const float* __restrict__ ln_b,
                  const unsigned short* __restrict__ q1b,
                  const unsigned short* __restrict__ k1b,
                  const unsigned short* __restrict__ v1b,
                  const unsigned short* __restrict__ k2b,
                  const unsigned short* __restrict__ v2b,
                  float* __restrict__ out) {
    extern __shared__ __align__(16) char smem[];
    unsigned short (*bufK)[256] = (unsigned short(*)[256])(smem + BK_OFF);
    unsigned short (*bufV)[256] = (unsigned short(*)[256])(smem + BV_OFF);
    unsigned short (*T1b)[264]  = (unsigned short(*)[264])(smem + T1B_OFF);
    unsigned short (*Sb)[264]   = (unsigned short(*)[264])(smem + SB_OFF);
    unsigned short (*Hb)[520]   = (unsigned short(*)[520])(smem + HB_OFF);
    unsigned char* actU         = (unsigned char*)(smem + ACT_OFF);
    float (*redA)[16]           = (float(*)[16])(smem + REDA_OFF);
    float (*redB)[16]           = (float(*)[16])(smem + REDB_OFF);
    float (*stats)[2]           = (float(*)[2])(smem + STAT_OFF);

    const int tid = threadIdx.x;              // 1024 threads, 16 waves
    const int wv = tid >> 6, lane = tid & 63;
    const int lr = lane & 15, qi = lane >> 4;
    const int m = wv;                         // attn: wave wv owns node wv
    const int bid = ((blockIdx.x & 7) << 5) | (blockIdx.x >> 3);   // XCD-chunked
    const int n0 = bid * 16;
    const int h = n0 >> 6, w0 = n0 & 63;

    // ---- P0: masks + K1/V1 unions via async DMA; prefetch q1 into regs ----
    dma_union(k1b, h, w0, 0, (unsigned short*)(smem + BK_OFF), tid);
    dma_union(v1b, h, w0, 0, (unsigned short*)(smem + BV_OFF), tid);
    float q[4];
    {
        short4v qv = *(const short4v*)(q1b + (size_t)(n0 + m) * 256 + lane * 4);
        #pragma unroll
        for (int j = 0; j < 4; ++j) q[j] = b2f(qv[j]);
    }
    if (tid < 100) {
        int r = tid / 20;
        int hh = h - 2 + r, ww = w0 - 2 + (tid - r * 20);
        actU[tid] = act_at(active, hh, ww) ? 1 : 0;
    }
    __syncthreads();

    // ---- A1: scores + in-register softmax + PV (barrier-free, wave-local) ----
    {
        float sc[L];
        #pragma unroll
        for (int l = 0; l < L; ++l) {
            int u = (l / 5) * 20 + m + (l % 5);
            short4v kv = *(const short4v*)&bufK[u][lane * 4];
            float p = q[0] * b2f(kv[0]);
            #pragma unroll
            for (int j = 1; j < 4; ++j) p = fmaf(q[j], b2f(kv[j]), p);
            p += __shfl_xor(p, 1); p += __shfl_xor(p, 2); p += __shfl_xor(p, 4);
            sc[l] = actU[u] ? p * SCALE : -1e30f;
        }
        float mx = sc[0];
        #pragma unroll
        for (int l = 1; l < L; ++l) mx = fmaxf(mx, sc[l]);
        float sum = 0.0f;
        #pragma unroll
        for (int l = 0; l < L; ++l) { sc[l] = expf(sc[l] - mx); sum += sc[l]; }
        float inv = 1.0f / sum;
        float o[4] = {0.f, 0.f, 0.f, 0.f};
        #pragma unroll
        for (int l = 0; l < L; ++l) {
            int u = (l / 5) * 20 + m + (l % 5);
            short4v v4 = *(const short4v*)&bufV[u][lane * 4];
            #pragma unroll
            for (int j = 0; j < 4; ++j) o[j] = fmaf(sc[l], b2f(v4[j]), o[j]);
        }
        unsigned short u8[4];
        #pragma unroll
        for (int j = 0; j < 4; ++j) u8[j] = f2b(o[j] * inv);
        *(uint2*)&T1b[m][lane * 4] = *(uint2*)u8;
    }
    __syncthreads();   // T1b ready; bufK/bufV dead

    // ---- P4: issue K2/V2 DMA; Wo1 + bias + resid(x) + LN0 -> sreg + Sb ----
    float sreg[4];
    {
        dma_union(k2b, h, w0, NN, (unsigned short*)(smem + BK_OFF), tid);
        dma_union(v2b, h, w0, NN, (unsigned short*)(smem + BV_OFF), tid);
        const unsigned short* Wo1T = wB + 3 * 65536;
        f32x4 acc = {};
        #pragma unroll
        for (int kk = 0; kk < 256; kk += 32) {
            short8 a = *(const short8*)&T1b[lr][qi * 8 + kk];
            short8 b = *(const short8*)(Wo1T + (size_t)(wv * 16 + lr) * 256 + qi * 8 + kk);
            acc = __builtin_amdgcn_mfma_f32_16x16x32_bf16(a, b, acc, 0, 0, 0);
        }
        const int c = wv * 16 + lr;
        float bc = attn_b[768 + c];
        float v[4], s1[4], s2[4];
        #pragma unroll
        for (int jj = 0; jj < 4; ++jj) {
            int row = n0 + qi * 4 + jj;
            float vv = acc[jj] + bc + x[(size_t)row * D + c];
            v[jj] = vv; s1[jj] = vv; s2[jj] = vv * vv;
        }
        #pragma unroll
        for (int jj = 0; jj < 4; ++jj) {
            #pragma unroll
            for (int off = 1; off < 16; off <<= 1) {
                s1[jj] += __shfl_xor(s1[jj], off);
                s2[jj] += __shfl_xor(s2[jj], off);
            }
        }
        if (lr == 0) {
            #pragma unroll
            for (int jj = 0; jj < 4; ++jj) { redA[qi*4+jj][wv] = s1[jj]; redB[qi*4+jj][wv] = s2[jj]; }
        }
        __syncthreads();
        if (tid < 16) {
            float a1 = 0.f, a2 = 0.f;
            #pragma unroll
            for (int q8 = 0; q8 < 16; ++q8) { a1 += redA[tid][q8]; a2 += redB[tid][q8]; }
            float mu = a1 * (1.0f / D);
            float var = a2 * (1.0f / D) - mu * mu;
            stats[tid][0] = mu; stats[tid][1] = rsqrtf(var + EPS);
        }
        __syncthreads();
        float gg = ln_g[c], bb = ln_b[c];
        #pragma unroll
        for (int jj = 0; jj < 4; ++jj) {
            int ridx = qi * 4 + jj;
            float ov = (v[jj] - stats[ridx][0]) * stats[ridx][1] * gg + bb;
            sreg[jj] = ov;
            Sb[ridx][c] = f2b(ov);
        }
    }
    __syncthreads();

    // ---- P5: Wq2 (Sb) -> T1b -> q2 regs ----
    float q2[4];
    {
        const unsigned short* Wq2T = wB + 4 * 65536;
        f32x4 acc = {};
        #pragma unroll
        for (int kk = 0; kk < 256; kk += 32) {
            short8 a = *(const short8*)&Sb[lr][qi * 8 + kk];
            short8 b = *(const short8*)(Wq2T + (size_t)(wv * 16 + lr) * 256 + qi * 8 + kk);
            acc = __builtin_amdgcn_mfma_f32_16x16x32_bf16(a, b, acc, 0, 0, 0);
        }
        const int c = wv * 16 + lr;
        float bc = pattn_b[c];
        #pragma unroll
        for (int jj = 0; jj < 4; ++jj)
            T1b[qi * 4 + jj][c] = f2b(acc[jj] + bc);
        __syncthreads();
        short4v qv = *(const short4v*)&T1b[m][lane * 4];
        #pragma unroll
        for (int j = 0; j < 4; ++j) q2[j] = b2f(qv[j]);
    }
    // (no barrier: wave m only overwrites its own T1b row m below)

    // ---- A2: scores + in-register softmax + PV (bufK=K2, bufV=V2) ----
    {
        float sc[L];
        #pragma unroll
        for (int l = 0; l < L; ++l) {
            int u = (l / 5) * 20 + m + (l % 5);
            short4v kv = *(const short4v*)&bufK[u][lane * 4];
            float p = q2[0] * b2f(kv[0]);
            #pragma unroll
            for (int j = 1; j < 4; ++j) p = fmaf(q2[j], b2f(kv[j]), p);
            p += __shfl_xor(p, 1); p += __shfl_xor(p, 2); p += __shfl_xor(p, 4);
            sc[l] = p * SCALE;
        }
        float mx = sc[0];
        #pragma unroll
        for (int l = 1; l < L; ++l) mx = fmaxf(mx, sc[l]);
        float sum = 0.0f;
        #pragma unroll
        for (int l = 0; l < L; ++l) { sc[l] = expf(sc[l] - mx); sum += sc[l]; }
        float inv = 1.0f / sum;
        float o[4] = {0.f, 0.f, 0.f, 0.f};
        #pragma unroll
        for (int l = 0; l < L; ++l) {
            int u = (l / 5) * 20 + m + (l % 5);
            short4v v4 = *(const short4v*)&bufV[u][lane * 4];
            #pragma unroll
            for (int j = 0; j < 4; ++j) o[j] = fmaf(sc[l], b2f(v4[j]), o[j]);
        }
        unsigned short u8[4];
        #pragma unroll
        for (int j = 0; j < 4; ++j) u8[j] = f2b(o[j] * inv);
        *(uint2*)&T1b[m][lane * 4] = *(uint2*)u8;
    }
    __syncthreads();

    // ---- P8: Wo2 + bias + resid(sreg) + LN2 -> s2reg + Sb ----
    float s2reg[4];
    {
        const unsigned short* Wo2T = wB + 7 * 65536;
        f32x4 acc = {};
        #pragma unroll
        for (int kk = 0; kk < 256; kk += 32) {
            short8 a = *(const short8*)&T1b[lr][qi * 8 + kk];
            short8 b = *(const short8*)(Wo2T + (size_t)(wv * 16 + lr) * 256 + qi * 8 + kk);
            acc = __builtin_amdgcn_mfma_f32_16x16x32_bf16(a, b, acc, 0, 0, 0);
        }
        const int c = wv * 16 + lr;
        float bc = pattn_b[768 + c];
        float v[4], s1[4], s2[4];
        #pragma unroll
        for (int jj = 0; jj < 4; ++jj) {
            float vv = acc[jj] + bc + sreg[jj];
            v[jj] = vv; s1[jj] = vv; s2[jj] = vv * vv;
        }
        #pragma unroll
        for (int jj = 0; jj < 4; ++jj) {
            #pragma unroll
            for (int off = 1; off < 16; off <<= 1) {
                s1[jj] += __shfl_xor(s1[jj], off);
                s2[jj] += __shfl_xor(s2[jj], off);
            }
        }
        if (lr == 0) {
            #pragma unroll
            for (int jj = 0; jj < 4; ++jj) { redA[qi*4+jj][wv] = s1[jj]; redB[qi*4+jj][wv] = s2[jj]; }
        }
        __syncthreads();
        if (tid < 16) {
            float a1 = 0.f, a2 = 0.f;
            #pragma unroll
            for (int q8 = 0; q8 < 16; ++q8) { a1 += redA[tid][q8]; a2 += redB[tid][q8]; }
            float mu = a1 * (1.0f / D);
            float var = a2 * (1.0f / D) - mu * mu;
            stats[tid][0] = mu; stats[tid][1] = rsqrtf(var + EPS);
        }
        __syncthreads();
        float gg = ln_g[512 + c], bb = ln_b[512 + c];
        #pragma unroll
        for (int jj = 0; jj < 4; ++jj) {
            int ridx = qi * 4 + jj;
            float ov = (v[jj] - stats[ridx][0]) * stats[ridx][1] * gg + bb;
            s2reg[jj] = ov;
            Sb[ridx][c] = f2b(ov);
        }
    }
    __syncthreads();

    // ---- P9: FF1 (Sb = S2) -> Hb (N=512: 16 waves x 32 cols) ----
    {
        const unsigned short* W1T = wB + 524288;
        f32x4 acc[2] = {};
        #pragma unroll
        for (int kk = 0; kk < 256; kk += 32) {
            short8 a = *(const short8*)&Sb[lr][qi * 8 + kk];
            #pragma unroll
            for (int nf = 0; nf < 2; ++nf) {
                short8 b = *(const short8*)(W1T + (size_t)(wv * 32 + nf * 16 + lr) * 256 + qi * 8 + kk);
                acc[nf] = __builtin_amdgcn_mfma_f32_16x16x32_bf16(a, b, acc[nf], 0, 0, 0);
            }
        }
        #pragma unroll
        for (int nf = 0; nf < 2; ++nf) {
            int c = wv * 32 + nf * 16 + lr;
            float bc = ff_b1[c];
            #pragma unroll
            for (int jj = 0; jj < 4; ++jj)
                Hb[qi * 4 + jj][c] = f2b(fmaxf(acc[nf][jj] + bc, 0.0f));
        }
    }
    __syncthreads();

    // ---- P10: FF2 (K=512) + resid(s2reg) + LN1 + mask -> out ----
    {
        const unsigned short* W2T = wB + 655360;
        f32x4 acc = {};
        #pragma unroll
        for (int kk = 0; kk < 512; kk += 32) {
            short8 a = *(const short8*)&Hb[lr][qi * 8 + kk];
            short8 b = *(const short8*)(W2T + (size_t)(wv * 16 + lr) * 512 + qi * 8 + kk);
            acc = __builtin_amdgcn_mfma_f32_16x16x32_bf16(a, b, acc, 0, 0, 0);
        }
        const int c = wv * 16 + lr;
        float bc = ff_b2[c];
        float v[4], s1[4], s2[4];
        #pragma unroll
        for (int jj = 0; jj < 4; ++jj) {
            float vv = acc[jj] + bc + s2reg[jj];
            v[jj] = vv; s1[jj] = vv; s2[jj] = vv * vv;
        }
        #pragma unroll
        for (int jj = 0; jj < 4; ++jj) {
            #pragma unroll
            for (int off = 1; off < 16; off <<= 1) {
                s1[jj] += __shfl_xor(s1[jj], off);
                s2[jj] += __shfl_xor(s2[jj], off);
            }
        }
        if (lr == 0) {
            #pragma unroll
            for (int jj = 0; jj < 4; ++jj) { redA[qi*4+jj][wv] = s1[jj]; redB[qi*4+jj][wv] = s2[jj]; }
        }
        __syncthreads();
        if (tid < 16) {
            float a1 = 0.f, a2 = 0.f;
            #pragma unroll
            for (int q8 = 0; q8 < 16; ++q8) { a1 += redA[tid][q8]; a2 += redB[tid][q8]; }
            float mu = a1 * (1.0f / D);
            float var = a2 * (1.0f / D) - mu * mu;
            stats[tid][0] = mu; stats[tid][1] = rsqrtf(var + EPS);
        }
        __syncthreads();
        bool arow_act[4];
        #pragma unroll
        for (int jj = 0; jj < 4; ++jj) {
            int row = n0 + qi * 4 + jj;
            arow_act[jj] = act_at(active, row >> 6, row & 63);
        }
        float gg = ln_g[256 + c], bb = ln_b[256 + c];
        #pragma unroll
        for (int jj = 0; jj < 4; ++jj) {
            int ridx = qi * 4 + jj;
            float ov = (v[jj] - stats[ridx][0]) * stats[ridx][1] * gg + bb;
            out[(size_t)(n0 + ridx) * D + c] = arow_act[jj] ? ov : 0.0f;
        }
        if (tid < 16) {
            int row = n0 + tid;
            out[(size_t)NND + row] = act_at(active, row >> 6, row & 63) ? 1.0f : 0.0f;
        }
    }
}

extern "C" void kernel_launch(void* const* d_in, const int* in_sizes, int n_in,
                              void* d_out, int out_size, void* d_ws, size_t ws_size,
                              hipStream_t stream) {
    const float* x       = (const float*)d_in[0];
    const float* memory  = (const float*)d_in[1];
    const int*   active  = (const int*)d_in[2];
    const float* attn_w  = (const float*)d_in[3];
    const float* attn_b  = (const float*)d_in[4];
    const float* pattn_w = (const float*)d_in[5];
    const float* pattn_b = (const float*)d_in[6];
    const float* ff_w1   = (const float*)d_in[7];
    const float* ff_b1   = (const float*)d_in[8];
    const float* ff_w2   = (const float*)d_in[9];
    const float* ff_b2   = (const float*)d_in[10];
    const float* ln_g    = (const float*)d_in[11];
    const float* ln_b    = (const float*)d_in[12];
    float* out = (float*)d_out;

    unsigned short* wsb = (unsigned short*)d_ws;
    unsigned short* xmB  = wsb;
    unsigned short* memB = wsb + (size_t)NND;
    unsigned short* wB   = wsb + 2 * (size_t)NND;               // 786432 shorts
    unsigned short* q1b  = wB + 786432;
    unsigned short* k1b  = q1b + (size_t)NND;
    unsigned short* v1b  = k1b + (size_t)NND;
    unsigned short* k2b  = v1b + (size_t)NND;                   // 4097 rows
    unsigned short* v2b  = k2b + (size_t)NND + 256;             // 4097 rows

    hipFuncSetAttribute(reinterpret_cast<const void*>(fused_kernel),
                        hipFuncAttributeMaxDynamicSharedMemorySize, SMEM_SZ);

    hipLaunchKernelGGL(prep_kernel, dim3(704), dim3(256), 0, stream,
                       x, memory, active, attn_w, pattn_w, ff_w1, ff_w2, pattn_b,
                       xmB, memB, wB, k2b + (size_t)NND, v2b + (size_t)NND);
    hipLaunchKernelGGL(proj_gemm, dim3(64, 20), dim3(256), 0, stream,
                       xmB, memB, wB, attn_b, pattn_b, q1b, k1b, v1b, k2b, v2b);
    hipLaunchKernelGGL(fused_kernel, dim3(256), dim3(1024), SMEM_SZ, stream,
                       active, x, wB, attn_b, pattn_b, ff_b1, ff_b2, ln_g, ln_b,
                       q1b, k1b, v1b, k2b, v2b, out);
}

// Round 17
// 83.993 us; speedup vs baseline: 4.1656x; 1.0138x over previous
//
#include <hip/hip_runtime.h>
#include <math.h>

#define D 256
#define H2 512
#define HEADS 8
#define L 25
#define GH 64
#define GW 64
#define NN 4096
#define EPS 1e-5f
#define SCALE 0.17677669529663687f  // 1/sqrt(32)
#define NND 1048576                 // NN*D

typedef __attribute__((ext_vector_type(8))) short short8;
typedef __attribute__((ext_vector_type(4))) short short4v;
typedef __attribute__((ext_vector_type(4))) float f32x4;

__device__ __forceinline__ bool act_at(const int* __restrict__ active, int h, int w) {
    if (h < 0 || h >= GH || w < 0 || w >= GW) return false;
    if (h == 2 && w == 2) return false;   // ap.at[:, center, center].set(False) quirk
    return active[h * GW + w] != 0;
}

__device__ __forceinline__ unsigned short f2b(float f) {
    unsigned u = __float_as_uint(f);
    u += 0x7fffu + ((u >> 16) & 1u);      // RNE
    return (unsigned short)(u >> 16);
}
__device__ __forceinline__ float b2f(short v) {
    return __uint_as_float(((unsigned)(unsigned short)v) << 16);
}

// async global->LDS DMA, 16 B per lane; lds dest = wave-uniform base + lane*16
__device__ __forceinline__ void dma16(const unsigned short* g, unsigned short* l) {
    __builtin_amdgcn_global_load_lds(
        (const __attribute__((address_space(1))) unsigned int*)g,
        (__attribute__((address_space(3))) unsigned int*)l, 16, 0, 0);
}

// ---------------- prep: bf16 conversions + LDS-tiled weight transposes ----------------
__global__ __launch_bounds__(256)
void prep_kernel(const float* __restrict__ x, const float* __restrict__ mem,
                 const int* __restrict__ active,
                 const float* __restrict__ attn_w, const float* __restrict__ pattn_w,
                 const float* __restrict__ ff_w1, const float* __restrict__ ff_w2,
                 const float* __restrict__ pattn_b,
                 unsigned short* __restrict__ xmB, unsigned short* __restrict__ memB,
                 unsigned short* __restrict__ wB,
                 unsigned short* __restrict__ k2bias, unsigned short* __restrict__ v2bias) {
    const int tid = threadIdx.x;
    const int bid = blockIdx.x;
    if (bid < 192) {
        __shared__ float tile[64][65];
        const float* src; unsigned short* dst;
        int i0, n0, srcLen, dstLen;
        if (bid < 128) {
            int mat = bid >> 4, t16 = bid & 15;
            i0 = (t16 >> 2) * 64; n0 = (t16 & 3) * 64;
            src = (mat < 4) ? (attn_w + mat * 65536) : (pattn_w + (mat - 4) * 65536);
            dst = wB + mat * 65536;
            srcLen = 256; dstLen = 256;
        } else if (bid < 160) {
            int t = bid - 128;
            i0 = (t >> 3) * 64; n0 = (t & 7) * 64;
            src = ff_w1; dst = wB + 524288;      // W1T: [512][256]
            srcLen = 512; dstLen = 256;
        } else {
            int t = bid - 160;
            i0 = (t >> 2) * 64; n0 = (t & 3) * 64;
            src = ff_w2; dst = wB + 655360;      // W2T: [256][512]
            srcLen = 256; dstLen = 512;
        }
        int c = tid & 63, r4 = tid >> 6;
        for (int rr = 0; rr < 64; rr += 4)
            tile[rr + r4][c] = src[(size_t)(i0 + rr + r4) * srcLen + n0 + c];
        __syncthreads();
        for (int rr = 0; rr < 64; rr += 4) {
            int r = rr + r4;
            dst[(size_t)(n0 + r) * dstLen + i0 + c] = f2b(tile[c][r]);
        }
    } else {
        const int t0 = (bid - 192) * 256 + tid;
        for (int t = t0; t < 524800; t += 512 * 256) {
            if (t < 262144) {
                int n = t >> 6;
                bool a = act_at(active, n >> 6, n & 63);
                float4 v = ((const float4*)x)[t];
                ushort4 u;
                u.x = f2b(a ? v.x : 0.0f); u.y = f2b(a ? v.y : 0.0f);
                u.z = f2b(a ? v.z : 0.0f); u.w = f2b(a ? v.w : 0.0f);
                ((ushort4*)xmB)[t] = u;
            } else if (t < 524288) {
                int tt = t - 262144;
                float4 v = ((const float4*)mem)[tt];
                ushort4 u;
                u.x = f2b(v.x); u.y = f2b(v.y); u.z = f2b(v.z); u.w = f2b(v.w);
                ((ushort4*)memB)[tt] = u;
            } else {
                int tt = t - 524288;
                if (tt < 256) k2bias[tt] = f2b(pattn_b[256 + tt]);
                else          v2bias[tt - 256] = f2b(pattn_b[512 + (tt - 256)]);
            }
        }
    }
}

// ---------------- proj: merged streams, XCD-aligned rows ----------------
// grid (64, 8): y<4 -> x source, streams {Q1,K1,V1}, col band (y&3)*64
//               y>=4 -> mem source, streams {K2,V2}
__global__ __launch_bounds__(256)
void proj_gemm(const unsigned short* __restrict__ xmB,
               const unsigned short* __restrict__ memB,
               const unsigned short* __restrict__ wB,
               const float* __restrict__ attn_b, const float* __restrict__ pattn_b,
               unsigned short* __restrict__ q1b, unsigned short* __restrict__ k1b,
               unsigned short* __restrict__ v1b, unsigned short* __restrict__ k2b,
               unsigned short* __restrict__ v2b) {
    const int grp = blockIdx.y >> 2;
    const int n0 = (blockIdx.y & 3) * 64;
    const unsigned short* A = grp ? memB : xmB;
    const int nst = grp ? 2 : 3;
    const unsigned short* W[3];
    const float* Bp[3];
    unsigned short* O[3];
    if (grp == 0) {
        W[0] = wB;             W[1] = wB + 65536;     W[2] = wB + 2 * 65536;
        Bp[0] = attn_b;        Bp[1] = attn_b + 256;  Bp[2] = attn_b + 512;
        O[0] = q1b;            O[1] = k1b;            O[2] = v1b;
    } else {
        W[0] = wB + 5 * 65536; W[1] = wB + 6 * 65536; W[2] = W[1];
        Bp[0] = pattn_b + 256; Bp[1] = pattn_b + 512; Bp[2] = Bp[1];
        O[0] = k2b;            O[1] = v2b;            O[2] = O[1];
    }

    const int tid = threadIdx.x;
    const int wave = tid >> 6, lane = tid & 63;
    // XCD k produces rows [k*512, k*512+512) — matches fused kernel's swizzle.
    const int xb = ((blockIdx.x & 7) << 3) | (blockIdx.x >> 3);
    const int m0 = xb * 64 + wave * 16;
    const int lr = lane & 15;
    const int lk = (lane >> 4) << 3;
    f32x4 acc[3][4] = {};
    const unsigned short* arow = A + (size_t)(m0 + lr) * 256 + lk;
    #pragma unroll
    for (int kk = 0; kk < 256; kk += 32) {
        short8 a = *(const short8*)(arow + kk);
        #pragma unroll
        for (int st = 0; st < 3; ++st) {
            if (st < nst) {
                const unsigned short* brow = W[st] + (size_t)(n0 + lr) * 256 + lk;
                #pragma unroll
                for (int nf = 0; nf < 4; ++nf) {
                    short8 b = *(const short8*)(brow + (size_t)nf * 16 * 256 + kk);
                    acc[st][nf] = __builtin_amdgcn_mfma_f32_16x16x32_bf16(a, b, acc[st][nf], 0, 0, 0);
                }
            }
        }
    }
    const int rbase = m0 + ((lane >> 4) << 2);
    #pragma unroll
    for (int st = 0; st < 3; ++st) {
        if (st < nst) {
            #pragma unroll
            for (int nf = 0; nf < 4; ++nf) {
                int c = n0 + nf * 16 + lr;
                float bc = Bp[st][c];
                #pragma unroll
                for (int jj = 0; jj < 4; ++jj)
                    O[st][(size_t)(rbase + jj) * 256 + c] = f2b(acc[st][nf][jj] + bc);
            }
        }
    }
}

// ---------------- dynamic LDS layout (138240 B) ----------------
#define BK_OFF   0            // K union: 100 x 256 bf16 = 51200
#define BV_OFF   51200        // V union: 51200
#define T1B_OFF  102400       // [16][264] bf16 = 8448
#define SB_OFF   110848       // [16][264] bf16 = 8448
#define HB_OFF   119296       // [16][520] bf16 = 16640
#define ACT_OFF  135936       // 128
#define REDA_OFF 136064       // [16][16] f32 = 1024
#define REDB_OFF 137088       // 1024
#define STAT_OFF 138112       // 128
#define SMEM_SZ  138240

__device__ __forceinline__ int union_row(int c, int h, int w0, int fallback) {
    int u = c >> 5;
    int r = u / 20;
    int hh = h - 2 + r, ww = w0 - 2 + (u - r * 20);
    bool ib = ((unsigned)hh < GH) && ((unsigned)ww < GW);
    return ib ? ((hh << 6) | ww) : fallback;
}

// 3200 chunks over 1024 threads: k<4, tail (k=3) = 2 full waves
__device__ __forceinline__ void dma_union(const unsigned short* __restrict__ base,
                                          int h, int w0, int fallback,
                                          unsigned short* dstLds, int tid) {
    #pragma unroll
    for (int k = 0; k < 4; ++k) {
        int c = tid + k * 1024;
        if (c < 3200) {
            int row = union_row(c, h, w0, fallback);
            dma16(base + (size_t)row * 256 + (c & 31) * 8, dstLds + (size_t)c * 8);
        }
    }
}

// ---------------- fused chain kernel: 1024 threads, 16 waves ----------------
__global__ __launch_bounds__(1024)
void fused_kernel(const int* __restrict__ active, const float* __restrict__ x,
                  const unsigned short* __restrict__ wB,
                  const float* __restrict__ attn_b, const float* __restrict__ pattn_b,
                  const float* __restrict__ ff_b1, const float* __restrict__ ff_b2,
                  const float* __restrict__ ln_g, const float* __restrict__ ln_b,
                  const unsigned short* __restrict__ q1b,
                  const unsigned short* __restrict__ k1b,
                  const unsigned short* __restrict__ v1b,
                  const unsigned short* __restrict__ k2b,
                  const unsigned short* __restrict__ v2b,
                  float* __restrict__ out) {
    extern __shared__ __align__(16) char smem[];
    unsigned short (*bufK)[256] = (unsigned short(*)[256])(smem + BK_OFF);
    unsigned short (*bufV)[256] = (unsigned short(*)[256])(smem + BV_OFF);
    unsigned short (*T1b)[264]  = (unsigned short(*)[264])(smem + T1B_OFF);
    unsigned short (*Sb)[264]   = (unsigned short(*)[264])(smem + SB_OFF);
    unsigned short (*Hb)[520]   = (unsigned short(*)[520])(smem + HB_OFF);
    unsigned char* actU         = (unsigned char*)(smem + ACT_OFF);
    float (*redA)[16]           = (float(*)[16])(smem + REDA_OFF);
    float (*redB)[16]           = (float(*)[16])(smem + REDB_OFF);
    float (*stats)[2]           = (float(*)[2])(smem + STAT_OFF);

    const int tid = threadIdx.x;              // 1024 threads, 16 waves
    const int wv = tid >> 6, lane = tid & 63;
    const int lr = lane & 15, qi = lane >> 4;
    const int m = wv;                         // attn: wave wv owns node wv
    const int bid = ((blockIdx.x & 7) << 5) | (blockIdx.x >> 3);   // XCD-chunked
    const int n0 = bid * 16;
    const int h = n0 >> 6, w0 = n0 & 63;

    // ---- P0: masks + K1/V1 unions via async DMA; prefetch q1 into regs ----
    dma_union(k1b, h, w0, 0, (unsigned short*)(smem + BK_OFF), tid);
    dma_union(v1b, h, w0, 0, (unsigned short*)(smem + BV_OFF), tid);
    float q[4];
    {
        short4v qv = *(const short4v*)(q1b + (size_t)(n0 + m) * 256 + lane * 4);
        #pragma unroll
        for (int j = 0; j < 4; ++j) q[j] = b2f(qv[j]);
    }
    if (tid < 100) {
        int r = tid / 20;
        int hh = h - 2 + r, ww = w0 - 2 + (tid - r * 20);
        actU[tid] = act_at(active, hh, ww) ? 1 : 0;
    }
    __syncthreads();

    // per-wave neighbor-activity bitmask (bit l = neighbor l of node m active)
    unsigned long long abal;
    {
        int lu = (lane < L) ? ((lane / 5) * 20 + m + (lane % 5)) : 0;
        int av = (lane < L) ? actU[lu] : 0;
        abal = __ballot(av != 0);
    }

    // ---- A1: scores + in-register softmax + PV (barrier-free, wave-local) ----
    {
        float sc[L];
        #pragma unroll
        for (int l = 0; l < L; ++l) {
            int u = (l / 5) * 20 + m + (l % 5);
            short4v kv = *(const short4v*)&bufK[u][lane * 4];
            float p = q[0] * b2f(kv[0]);
            #pragma unroll
            for (int j = 1; j < 4; ++j) p = fmaf(q[j], b2f(kv[j]), p);
            p += __shfl_xor(p, 1); p += __shfl_xor(p, 2); p += __shfl_xor(p, 4);
            sc[l] = ((abal >> l) & 1ull) ? p * SCALE : -1e30f;
        }
        float mx = sc[0];
        #pragma unroll
        for (int l = 1; l < L; ++l) mx = fmaxf(mx, sc[l]);
        float sum = 0.0f;
        #pragma unroll
        for (int l = 0; l < L; ++l) { sc[l] = expf(sc[l] - mx); sum += sc[l]; }
        float inv = 1.0f / sum;
        float o[4] = {0.f, 0.f, 0.f, 0.f};
        #pragma unroll
        for (int l = 0; l < L; ++l) {
            if ((abal >> l) & 1ull) {
                int u = (l / 5) * 20 + m + (l % 5);
                short4v v4 = *(const short4v*)&bufV[u][lane * 4];
                #pragma unroll
                for (int j = 0; j < 4; ++j) o[j] = fmaf(sc[l], b2f(v4[j]), o[j]);
            }
        }
        unsigned short u8[4];
        #pragma unroll
        for (int j = 0; j < 4; ++j) u8[j] = f2b(o[j] * inv);
        *(uint2*)&T1b[m][lane * 4] = *(uint2*)u8;
    }
    __syncthreads();   // T1b ready; bufK/bufV dead

    // ---- P4: issue K2/V2 DMA; Wo1 + bias + resid(x) + LN0 -> sreg + Sb ----
    float sreg[4];
    {
        dma_union(k2b, h, w0, NN, (unsigned short*)(smem + BK_OFF), tid);
        dma_union(v2b, h, w0, NN, (unsigned short*)(smem + BV_OFF), tid);
        const unsigned short* Wo1T = wB + 3 * 65536;
        f32x4 acc = {};
        #pragma unroll
        for (int kk = 0; kk < 256; kk += 32) {
            short8 a = *(const short8*)&T1b[lr][qi * 8 + kk];
            short8 b = *(const short8*)(Wo1T + (size_t)(wv * 16 + lr) * 256 + qi * 8 + kk);
            acc = __builtin_amdgcn_mfma_f32_16x16x32_bf16(a, b, acc, 0, 0, 0);
        }
        const int c = wv * 16 + lr;
        float bc = attn_b[768 + c];
        float v[4], s1[4], s2[4];
        #pragma unroll
        for (int jj = 0; jj < 4; ++jj) {
            int row = n0 + qi * 4 + jj;
            float vv = acc[jj] + bc + x[(size_t)row * D + c];
            v[jj] = vv; s1[jj] = vv; s2[jj] = vv * vv;
        }
        #pragma unroll
        for (int jj = 0; jj < 4; ++jj) {
            #pragma unroll
            for (int off = 1; off < 16; off <<= 1) {
                s1[jj] += __shfl_xor(s1[jj], off);
                s2[jj] += __shfl_xor(s2[jj], off);
            }
        }
        if (lr == 0) {
            #pragma unroll
            for (int jj = 0; jj < 4; ++jj) { redA[qi*4+jj][wv] = s1[jj]; redB[qi*4+jj][wv] = s2[jj]; }
        }
        __syncthreads();
        if (tid < 16) {
            float a1 = 0.f, a2 = 0.f;
            #pragma unroll
            for (int q8 = 0; q8 < 16; ++q8) { a1 += redA[tid][q8]; a2 += redB[tid][q8]; }
            float mu = a1 * (1.0f / D);
            float var = a2 * (1.0f / D) - mu * mu;
            stats[tid][0] = mu; stats[tid][1] = rsqrtf(var + EPS);
        }
        __syncthreads();
        float gg = ln_g[c], bb = ln_b[c];
        #pragma unroll
        for (int jj = 0; jj < 4; ++jj) {
            int ridx = qi * 4 + jj;
            float ov = (v[jj] - stats[ridx][0]) * stats[ridx][1] * gg + bb;
            sreg[jj] = ov;
            Sb[ridx][c] = f2b(ov);
        }
    }
    __syncthreads();

    // ---- P5: Wq2 (Sb) -> T1b -> q2 regs ----
    float q2[4];
    {
        const unsigned short* Wq2T = wB + 4 * 65536;
        f32x4 acc = {};
        #pragma unroll
        for (int kk = 0; kk < 256; kk += 32) {
            short8 a = *(const short8*)&Sb[lr][qi * 8 + kk];
            short8 b = *(const short8*)(Wq2T + (size_t)(wv * 16 + lr) * 256 + qi * 8 + kk);
            acc = __builtin_amdgcn_mfma_f32_16x16x32_bf16(a, b, acc, 0, 0, 0);
        }
        const int c = wv * 16 + lr;
        float bc = pattn_b[c];
        #pragma unroll
        for (int jj = 0; jj < 4; ++jj)
            T1b[qi * 4 + jj][c] = f2b(acc[jj] + bc);
        __syncthreads();
        short4v qv = *(const short4v*)&T1b[m][lane * 4];
        #pragma unroll
        for (int j = 0; j < 4; ++j) q2[j] = b2f(qv[j]);
    }
    // (no barrier: wave m only overwrites its own T1b row m below)

    // ---- A2: scores + in-register softmax + PV (bufK=K2, bufV=V2) ----
    {
        float sc[L];
        #pragma unroll
        for (int l = 0; l < L; ++l) {
            int u = (l / 5) * 20 + m + (l % 5);
            short4v kv = *(const short4v*)&bufK[u][lane * 4];
            float p = q2[0] * b2f(kv[0]);
            #pragma unroll
            for (int j = 1; j < 4; ++j) p = fmaf(q2[j], b2f(kv[j]), p);
            p += __shfl_xor(p, 1); p += __shfl_xor(p, 2); p += __shfl_xor(p, 4);
            sc[l] = p * SCALE;
        }
        float mx = sc[0];
        #pragma unroll
        for (int l = 1; l < L; ++l) mx = fmaxf(mx, sc[l]);
        float sum = 0.0f;
        #pragma unroll
        for (int l = 0; l < L; ++l) { sc[l] = expf(sc[l] - mx); sum += sc[l]; }
        float inv = 1.0f / sum;
        float o[4] = {0.f, 0.f, 0.f, 0.f};
        #pragma unroll
        for (int l = 0; l < L; ++l) {
            int u = (l / 5) * 20 + m + (l % 5);
            short4v v4 = *(const short4v*)&bufV[u][lane * 4];
            #pragma unroll
            for (int j = 0; j < 4; ++j) o[j] = fmaf(sc[l], b2f(v4[j]), o[j]);
        }
        unsigned short u8[4];
        #pragma unroll
        for (int j = 0; j < 4; ++j) u8[j] = f2b(o[j] * inv);
        *(uint2*)&T1b[m][lane * 4] = *(uint2*)u8;
    }
    __syncthreads();

    // ---- P8: Wo2 + bias + resid(sreg) + LN2 -> s2reg + Sb ----
    float s2reg[4];
    {
        const unsigned short* Wo2T = wB + 7 * 65536;
        f32x4 acc = {};
        #pragma unroll
        for (int kk = 0; kk < 256; kk += 32) {
            short8 a = *(const short8*)&T1b[lr][qi * 8 + kk];
            short8 b = *(const short8*)(Wo2T + (size_t)(wv * 16 + lr) * 256 + qi * 8 + kk);
            acc = __builtin_amdgcn_mfma_f32_16x16x32_bf16(a, b, acc, 0, 0, 0);
        }
        const int c = wv * 16 + lr;
        float bc = pattn_b[768 + c];
        float v[4], s1[4], s2[4];
        #pragma unroll
        for (int jj = 0; jj < 4; ++jj) {
            float vv = acc[jj] + bc + sreg[jj];
            v[jj] = vv; s1[jj] = vv; s2[jj] = vv * vv;
        }
        #pragma unroll
        for (int jj = 0; jj < 4; ++jj) {
            #pragma unroll
            for (int off = 1; off < 16; off <<= 1) {
                s1[jj] += __shfl_xor(s1[jj], off);
                s2[jj] += __shfl_xor(s2[jj], off);
            }
        }
        if (lr == 0) {
            #pragma unroll
            for (int jj = 0; jj < 4; ++jj) { redA[qi*4+jj][wv] = s1[jj]; redB[qi*4+jj][wv] = s2[jj]; }
        }
        __syncthreads();
        if (tid < 16) {
            float a1 = 0.f, a2 = 0.f;
            #pragma unroll
            for (int q8 = 0; q8 < 16; ++q8) { a1 += redA[tid][q8]; a2 += redB[tid][q8]; }
            float mu = a1 * (1.0f / D);
            float var = a2 * (1.0f / D) - mu * mu;
            stats[tid][0] = mu; stats[tid][1] = rsqrtf(var + EPS);
        }
        __syncthreads();
        float gg = ln_g[512 + c], bb = ln_b[512 + c];
        #pragma unroll
        for (int jj = 0; jj < 4; ++jj) {
            int ridx = qi * 4 + jj;
            float ov = (v[jj] - stats[ridx][0]) * stats[ridx][1] * gg + bb;
            s2reg[jj] = ov;
            Sb[ridx][c] = f2b(ov);
        }
    }
    __syncthreads();

    // ---- P9: FF1 (Sb = S2) -> Hb (N=512: 16 waves x 32 cols) ----
    {
        const unsigned short* W1T = wB + 524288;
        f32x4 acc[2] = {};
        #pragma unroll
        for (int kk = 0; kk < 256; kk += 32) {
            short8 a = *(const short8*)&Sb[lr][qi * 8 + kk];
            #pragma unroll
            for (int nf = 0; nf < 2; ++nf) {
                short8 b = *(const short8*)(W1T + (size_t)(wv * 32 + nf * 16 + lr) * 256 + qi * 8 + kk);
                acc[nf] = __builtin_amdgcn_mfma_f32_16x16x32_bf16(a, b, acc[nf], 0, 0, 0);
            }
        }
        #pragma unroll
        for (int nf = 0; nf < 2; ++nf) {
            int c = wv * 32 + nf * 16 + lr;
            float bc = ff_b1[c];
            #pragma unroll
            for (int jj = 0; jj < 4; ++jj)
                Hb[qi * 4 + jj][c] = f2b(fmaxf(acc[nf][jj] + bc, 0.0f));
        }
    }
    __syncthreads();

    // ---- P10: FF2 (K=512) + resid(s2reg) + LN1 + mask -> out ----
    {
        const unsigned short* W2T = wB + 655360;
        f32x4 acc = {};
        #pragma unroll
        for (int kk = 0; kk < 512; kk += 32) {
            short8 a = *(const short8*)&Hb[lr][qi * 8 + kk];
            short8 b = *(const short8*)(W2T + (size_t)(wv * 16 + lr) * 512 + qi * 8 + kk);
            acc = __builtin_amdgcn_mfma_f32_16x16x32_bf16(a, b, acc, 0, 0, 0);
        }
        const int c = wv * 16 + lr;
        float bc = ff_b2[c];
        float v[4], s1[4], s2[4];
        #pragma unroll
        for (int jj = 0; jj < 4; ++jj) {
            float vv = acc[jj] + bc + s2reg[jj];
            v[jj] = vv; s1[jj] = vv; s2[jj] = vv * vv;
        }
        #pragma unroll
        for (int jj = 0; jj < 4; ++jj) {
            #pragma unroll
            for (int off = 1; off < 16; off <<= 1) {
                s1[jj] += __shfl_xor(s1[jj], off);
                s2[jj] += __shfl_xor(s2[jj], off);
            }
        }
        if (lr == 0) {
            #pragma unroll
            for (int jj = 0; jj < 4; ++jj) { redA[qi*4+jj][wv] = s1[jj]; redB[qi*4+jj][wv] = s2[jj]; }
        }
        __syncthreads();
        if (tid < 16) {
            float a1 = 0.f, a2 = 0.f;
            #pragma unroll
            for (int q8 = 0; q8 < 16; ++q8) { a1 += redA[tid][q8]; a2 += redB[tid][q8]; }
            float mu = a1 * (1.0f / D);
            float var = a2 * (1.0f / D) - mu * mu;
            stats[tid][0] = mu; stats[tid][1] = rsqrtf(var + EPS);
        }
        __syncthreads();
        bool arow_act[4];
        #pragma unroll
        for (int jj = 0; jj < 4; ++jj) {
            int row = n0 + qi * 4 + jj;
            arow_act[jj] = act_at(active, row >> 6, row & 63);
        }
        float gg = ln_g[256 + c], bb = ln_b[256 + c];
        #pragma unroll
        for (int jj = 0; jj < 4; ++jj) {
            int ridx = qi * 4 + jj;
            float ov = (v[jj] - stats[ridx][0]) * stats[ridx][1] * gg + bb;
            out[(size_t)(n0 + ridx) * D + c] = arow_act[jj] ? ov : 0.0f;
        }
        if (tid < 16) {
            int row = n0 + tid;
            out[(size_t)NND + row] = act_at(active, row >> 6, row & 63) ? 1.0f : 0.0f;
        }
    }
}

extern "C" void kernel_launch(void* const* d_in, const int* in_sizes, int n_in,
                              void* d_out, int out_size, void* d_ws, size_t ws_size,
                              hipStream_t stream) {
    const float* x       = (const float*)d_in[0];
    const float* memory  = (const float*)d_in[1];
    const int*   active  = (const int*)d_in[2];
    const float* attn_w  = (const float*)d_in[3];
    const float* attn_b  = (const float*)d_in[4];
    const float* pattn_w = (const float*)d_in[5];
    const float* pattn_b = (const float*)d_in[6];
    const float* ff_w1   = (const float*)d_in[7];
    const float* ff_b1   = (const float*)d_in[8];
    const float* ff_w2   = (const float*)d_in[9];
    const float* ff_b2   = (const float*)d_in[10];
    const float* ln_g    = (const float*)d_in[11];
    const float* ln_b    = (const float*)d_in[12];
    float* out = (float*)d_out;

    unsigned short* wsb = (unsigned short*)d_ws;
    unsigned short* xmB  = wsb;
    unsigned short* memB = wsb + (size_t)NND;
    unsigned short* wB   = wsb + 2 * (size_t)NND;               // 786432 shorts
    unsigned short* q1b  = wB + 786432;
    unsigned short* k1b  = q1b + (size_t)NND;
    unsigned short* v1b  = k1b + (size_t)NND;
    unsigned short* k2b  = v1b + (size_t)NND;                   // 4097 rows
    unsigned short* v2b  = k2b + (size_t)NND + 256;             // 4097 rows

    hipFuncSetAttribute(reinterpret_cast<const void*>(fused_kernel),
                        hipFuncAttributeMaxDynamicSharedMemorySize, SMEM_SZ);

    hipLaunchKernelGGL(prep_kernel, dim3(704), dim3(256), 0, stream,
                       x, memory, active, attn_w, pattn_w, ff_w1, ff_w2, pattn_b,
                       xmB, memB, wB, k2b + (size_t)NND, v2b + (size_t)NND);
    hipLaunchKernelGGL(proj_gemm, dim3(64, 8), dim3(256), 0, stream,
                       xmB, memB, wB, attn_b, pattn_b, q1b, k1b, v1b, k2b, v2b);
    hipLaunchKernelGGL(fused_kernel, dim3(256), dim3(1024), SMEM_SZ, stream,
                       active, x, wB, attn_b, pattn_b, ff_b1, ff_b2, ln_g, ln_b,
                       q1b, k1b, v1b, k2b, v2b, out);
}

// Round 18
// 83.394 us; speedup vs baseline: 4.1955x; 1.0072x over previous
//
#include <hip/hip_runtime.h>
#include <math.h>

#define D 256
#define H2 512
#define HEADS 8
#define L 25
#define GH 64
#define GW 64
#define NN 4096
#define EPS 1e-5f
#define SCALE 0.17677669529663687f  // 1/sqrt(32)
#define NND 1048576                 // NN*D

typedef __attribute__((ext_vector_type(8))) short short8;
typedef __attribute__((ext_vector_type(4))) short short4v;
typedef __attribute__((ext_vector_type(4))) float f32x4;

__device__ __forceinline__ bool act_at(const int* __restrict__ active, int h, int w) {
    if (h < 0 || h >= GH || w < 0 || w >= GW) return false;
    if (h == 2 && w == 2) return false;   // ap.at[:, center, center].set(False) quirk
    return active[h * GW + w] != 0;
}

__device__ __forceinline__ unsigned short f2b(float f) {
    unsigned u = __float_as_uint(f);
    u += 0x7fffu + ((u >> 16) & 1u);      // RNE
    return (unsigned short)(u >> 16);
}
__device__ __forceinline__ float b2f(short v) {
    return __uint_as_float(((unsigned)(unsigned short)v) << 16);
}

// async global->LDS DMA, 16 B per lane; lds dest = wave-uniform base + lane*16
__device__ __forceinline__ void dma16(const unsigned short* g, unsigned short* l) {
    __builtin_amdgcn_global_load_lds(
        (const __attribute__((address_space(1))) unsigned int*)g,
        (__attribute__((address_space(3))) unsigned int*)l, 16, 0, 0);
}

// ---------------- prep: bf16 conversions + LDS-tiled weight transposes ----------------
__global__ __launch_bounds__(256)
void prep_kernel(const float* __restrict__ x, const float* __restrict__ mem,
                 const int* __restrict__ active,
                 const float* __restrict__ attn_w, const float* __restrict__ pattn_w,
                 const float* __restrict__ ff_w1, const float* __restrict__ ff_w2,
                 const float* __restrict__ pattn_b,
                 unsigned short* __restrict__ xmB, unsigned short* __restrict__ memB,
                 unsigned short* __restrict__ wB,
                 unsigned short* __restrict__ k2bias, unsigned short* __restrict__ v2bias) {
    const int tid = threadIdx.x;
    const int bid = blockIdx.x;
    if (bid < 192) {
        __shared__ float tile[64][65];
        const float* src; unsigned short* dst;
        int i0, n0, srcLen, dstLen;
        if (bid < 128) {
            int mat = bid >> 4, t16 = bid & 15;
            i0 = (t16 >> 2) * 64; n0 = (t16 & 3) * 64;
            src = (mat < 4) ? (attn_w + mat * 65536) : (pattn_w + (mat - 4) * 65536);
            dst = wB + mat * 65536;
            srcLen = 256; dstLen = 256;
        } else if (bid < 160) {
            int t = bid - 128;
            i0 = (t >> 3) * 64; n0 = (t & 7) * 64;
            src = ff_w1; dst = wB + 524288;      // W1T: [512][256]
            srcLen = 512; dstLen = 256;
        } else {
            int t = bid - 160;
            i0 = (t >> 2) * 64; n0 = (t & 3) * 64;
            src = ff_w2; dst = wB + 655360;      // W2T: [256][512]
            srcLen = 256; dstLen = 512;
        }
        int c = tid & 63, r4 = tid >> 6;
        for (int rr = 0; rr < 64; rr += 4)
            tile[rr + r4][c] = src[(size_t)(i0 + rr + r4) * srcLen + n0 + c];
        __syncthreads();
        for (int rr = 0; rr < 64; rr += 4) {
            int r = rr + r4;
            dst[(size_t)(n0 + r) * dstLen + i0 + c] = f2b(tile[c][r]);
        }
    } else {
        const int t0 = (bid - 192) * 256 + tid;
        for (int t = t0; t < 524800; t += 512 * 256) {
            if (t < 262144) {
                int n = t >> 6;
                bool a = act_at(active, n >> 6, n & 63);
                float4 v = ((const float4*)x)[t];
                ushort4 u;
                u.x = f2b(a ? v.x : 0.0f); u.y = f2b(a ? v.y : 0.0f);
                u.z = f2b(a ? v.z : 0.0f); u.w = f2b(a ? v.w : 0.0f);
                ((ushort4*)xmB)[t] = u;
            } else if (t < 524288) {
                int tt = t - 262144;
                float4 v = ((const float4*)mem)[tt];
                ushort4 u;
                u.x = f2b(v.x); u.y = f2b(v.y); u.z = f2b(v.z); u.w = f2b(v.w);
                ((ushort4*)memB)[tt] = u;
            } else {
                int tt = t - 524288;
                if (tt < 256) k2bias[tt] = f2b(pattn_b[256 + tt]);
                else          v2bias[tt - 256] = f2b(pattn_b[512 + (tt - 256)]);
            }
        }
    }
}

// ---------------- proj: merged streams, XCD-aligned rows ----------------
__global__ __launch_bounds__(256)
void proj_gemm(const unsigned short* __restrict__ xmB,
               const unsigned short* __restrict__ memB,
               const unsigned short* __restrict__ wB,
               const float* __restrict__ attn_b, const float* __restrict__ pattn_b,
               unsigned short* __restrict__ q1b, unsigned short* __restrict__ k1b,
               unsigned short* __restrict__ v1b, unsigned short* __restrict__ k2b,
               unsigned short* __restrict__ v2b) {
    const int grp = blockIdx.y >> 2;
    const int n0 = (blockIdx.y & 3) * 64;
    const unsigned short* A = grp ? memB : xmB;
    const int nst = grp ? 2 : 3;
    const unsigned short* W[3];
    const float* Bp[3];
    unsigned short* O[3];
    if (grp == 0) {
        W[0] = wB;             W[1] = wB + 65536;     W[2] = wB + 2 * 65536;
        Bp[0] = attn_b;        Bp[1] = attn_b + 256;  Bp[2] = attn_b + 512;
        O[0] = q1b;            O[1] = k1b;            O[2] = v1b;
    } else {
        W[0] = wB + 5 * 65536; W[1] = wB + 6 * 65536; W[2] = W[1];
        Bp[0] = pattn_b + 256; Bp[1] = pattn_b + 512; Bp[2] = Bp[1];
        O[0] = k2b;            O[1] = v2b;            O[2] = O[1];
    }

    const int tid = threadIdx.x;
    const int wave = tid >> 6, lane = tid & 63;
    const int xb = ((blockIdx.x & 7) << 3) | (blockIdx.x >> 3);
    const int m0 = xb * 64 + wave * 16;
    const int lr = lane & 15;
    const int lk = (lane >> 4) << 3;
    f32x4 acc[3][4] = {};
    const unsigned short* arow = A + (size_t)(m0 + lr) * 256 + lk;
    #pragma unroll
    for (int kk = 0; kk < 256; kk += 32) {
        short8 a = *(const short8*)(arow + kk);
        #pragma unroll
        for (int st = 0; st < 3; ++st) {
            if (st < nst) {
                const unsigned short* brow = W[st] + (size_t)(n0 + lr) * 256 + lk;
                #pragma unroll
                for (int nf = 0; nf < 4; ++nf) {
                    short8 b = *(const short8*)(brow + (size_t)nf * 16 * 256 + kk);
                    acc[st][nf] = __builtin_amdgcn_mfma_f32_16x16x32_bf16(a, b, acc[st][nf], 0, 0, 0);
                }
            }
        }
    }
    const int rbase = m0 + ((lane >> 4) << 2);
    #pragma unroll
    for (int st = 0; st < 3; ++st) {
        if (st < nst) {
            #pragma unroll
            for (int nf = 0; nf < 4; ++nf) {
                int c = n0 + nf * 16 + lr;
                float bc = Bp[st][c];
                #pragma unroll
                for (int jj = 0; jj < 4; ++jj)
                    O[st][(size_t)(rbase + jj) * 256 + c] = f2b(acc[st][nf][jj] + bc);
            }
        }
    }
}

// ---------------- dynamic LDS layout (138240 B) ----------------
#define BK_OFF   0
#define BV_OFF   51200
#define T1B_OFF  102400
#define SB_OFF   110848
#define HB_OFF   119296
#define ACT_OFF  135936
#define REDA_OFF 136064       // [16][16] f32 = 1024
#define REDB_OFF 137088       // 1024
#define STAT_OFF 138112       // unused
#define SMEM_SZ  138240

__device__ __forceinline__ int union_row(int c, int h, int w0, int fallback) {
    int u = c >> 5;
    int r = u / 20;
    int hh = h - 2 + r, ww = w0 - 2 + (u - r * 20);
    bool ib = ((unsigned)hh < GH) && ((unsigned)ww < GW);
    return ib ? ((hh << 6) | ww) : fallback;
}

__device__ __forceinline__ void dma_union(const unsigned short* __restrict__ base,
                                          int h, int w0, int fallback,
                                          unsigned short* dstLds, int tid) {
    #pragma unroll
    for (int k = 0; k < 4; ++k) {
        int c = tid + k * 1024;
        if (c < 3200) {
            int row = union_row(c, h, w0, fallback);
            dma16(base + (size_t)row * 256 + (c & 31) * 8, dstLds + (size_t)c * 8);
        }
    }
}

// single-barrier batched LN: v[4] = rows qi*4+jj at col c; normalizes in place.
__device__ __forceinline__ void ln_sb(float* v, float (*rA)[16], float (*rB)[16],
                                      int lr, int qi, int wv, float gg, float bb) {
    float s1[4], s2[4];
    #pragma unroll
    for (int jj = 0; jj < 4; ++jj) { s1[jj] = v[jj]; s2[jj] = v[jj] * v[jj]; }
    #pragma unroll
    for (int jj = 0; jj < 4; ++jj) {
        #pragma unroll
        for (int off = 1; off < 16; off <<= 1) {
            s1[jj] += __shfl_xor(s1[jj], off);
            s2[jj] += __shfl_xor(s2[jj], off);
        }
    }
    if (lr == 0) {
        #pragma unroll
        for (int jj = 0; jj < 4; ++jj) { rA[qi * 4 + jj][wv] = s1[jj]; rB[qi * 4 + jj][wv] = s2[jj]; }
    }
    __syncthreads();
    #pragma unroll
    for (int jj = 0; jj < 4; ++jj) {
        int ridx = qi * 4 + jj;
        const float4* pa = (const float4*)rA[ridx];
        const float4* pb = (const float4*)rB[ridx];
        float a1 = 0.f, a2 = 0.f;
        #pragma unroll
        for (int qd = 0; qd < 4; ++qd) {
            float4 va = pa[qd], vb = pb[qd];
            a1 += va.x + va.y + va.z + va.w;
            a2 += vb.x + vb.y + vb.z + vb.w;
        }
        float mu = a1 * (1.0f / D);
        float var = a2 * (1.0f / D) - mu * mu;
        float rstd = rsqrtf(var + EPS);
        v[jj] = (v[jj] - mu) * rstd * gg + bb;
    }
}

// ---------------- fused chain kernel: 1024 threads, 16 waves ----------------
__global__ __launch_bounds__(1024)
void fused_kernel(const int* __restrict__ active, const float* __restrict__ x,
                  const unsigned short* __restrict__ wB,
                  const float* __restrict__ attn_b, const float* __restrict__ pattn_b,
                  const float* __restrict__ ff_b1, const float* __restrict__ ff_b2,
                  const float* __restrict__ ln_g, const float* __restrict__ ln_b,
                  const unsigned short* __restrict__ q1b,
                  const unsigned short* __restrict__ k1b,
                  const unsigned short* __restrict__ v1b,
                  const unsigned short* __restrict__ k2b,
                  const unsigned short* __restrict__ v2b,
                  float* __restrict__ out) {
    extern __shared__ __align__(16) char smem[];
    unsigned short (*bufK)[256] = (unsigned short(*)[256])(smem + BK_OFF);
    unsigned short (*bufV)[256] = (unsigned short(*)[256])(smem + BV_OFF);
    unsigned short (*T1b)[264]  = (unsigned short(*)[264])(smem + T1B_OFF);
    unsigned short (*Sb)[264]   = (unsigned short(*)[264])(smem + SB_OFF);
    unsigned short (*Hb)[520]   = (unsigned short(*)[520])(smem + HB_OFF);
    unsigned char* actU         = (unsigned char*)(smem + ACT_OFF);
    float (*redA)[16]           = (float(*)[16])(smem + REDA_OFF);
    float (*redB)[16]           = (float(*)[16])(smem + REDB_OFF);

    const int tid = threadIdx.x;
    const int wv = tid >> 6, lane = tid & 63;
    const int lr = lane & 15, qi = lane >> 4;
    const int m = wv;
    const int bid = ((blockIdx.x & 7) << 5) | (blockIdx.x >> 3);   // XCD-chunked
    const int n0 = bid * 16;
    const int h = n0 >> 6, w0 = n0 & 63;

    // ---- P0: masks + K1/V1 unions via async DMA; prefetch q1 into regs ----
    dma_union(k1b, h, w0, 0, (unsigned short*)(smem + BK_OFF), tid);
    dma_union(v1b, h, w0, 0, (unsigned short*)(smem + BV_OFF), tid);
    float q[4];
    {
        short4v qv = *(const short4v*)(q1b + (size_t)(n0 + m) * 256 + lane * 4);
        #pragma unroll
        for (int j = 0; j < 4; ++j) q[j] = b2f(qv[j]);
    }
    if (tid < 100) {
        int r = tid / 20;
        int hh = h - 2 + r, ww = w0 - 2 + (tid - r * 20);
        actU[tid] = act_at(active, hh, ww) ? 1 : 0;
    }
    __syncthreads();

    unsigned long long abal;
    {
        int lu = (lane < L) ? ((lane / 5) * 20 + m + (lane % 5)) : 0;
        int av = (lane < L) ? actU[lu] : 0;
        abal = __ballot(av != 0);
    }

    // ---- A1: scores + in-register softmax + PV ----
    {
        float sc[L];
        #pragma unroll
        for (int l = 0; l < L; ++l) {
            int u = (l / 5) * 20 + m + (l % 5);
            short4v kv = *(const short4v*)&bufK[u][lane * 4];
            float p = q[0] * b2f(kv[0]);
            #pragma unroll
            for (int j = 1; j < 4; ++j) p = fmaf(q[j], b2f(kv[j]), p);
            p += __shfl_xor(p, 1); p += __shfl_xor(p, 2); p += __shfl_xor(p, 4);
            sc[l] = ((abal >> l) & 1ull) ? p * SCALE : -1e30f;
        }
        float mx = sc[0];
        #pragma unroll
        for (int l = 1; l < L; ++l) mx = fmaxf(mx, sc[l]);
        float sum = 0.0f;
        #pragma unroll
        for (int l = 0; l < L; ++l) { sc[l] = __expf(sc[l] - mx); sum += sc[l]; }
        float inv = 1.0f / sum;
        float o[4] = {0.f, 0.f, 0.f, 0.f};
        #pragma unroll
        for (int l = 0; l < L; ++l) {
            if ((abal >> l) & 1ull) {
                int u = (l / 5) * 20 + m + (l % 5);
                short4v v4 = *(const short4v*)&bufV[u][lane * 4];
                #pragma unroll
                for (int j = 0; j < 4; ++j) o[j] = fmaf(sc[l], b2f(v4[j]), o[j]);
            }
        }
        unsigned short u8[4];
        #pragma unroll
        for (int j = 0; j < 4; ++j) u8[j] = f2b(o[j] * inv);
        *(uint2*)&T1b[m][lane * 4] = *(uint2*)u8;
    }
    __syncthreads();   // T1b ready; bufK/bufV dead

    // ---- P4: issue K2/V2 DMA; Wo1 + bias + resid(x) + LN0 -> sreg + Sb ----
    float sreg[4];
    {
        dma_union(k2b, h, w0, NN, (unsigned short*)(smem + BK_OFF), tid);
        dma_union(v2b, h, w0, NN, (unsigned short*)(smem + BV_OFF), tid);
        const unsigned short* Wo1T = wB + 3 * 65536;
        f32x4 acc = {};
        #pragma unroll
        for (int kk = 0; kk < 256; kk += 32) {
            short8 a = *(const short8*)&T1b[lr][qi * 8 + kk];
            short8 b = *(const short8*)(Wo1T + (size_t)(wv * 16 + lr) * 256 + qi * 8 + kk);
            acc = __builtin_amdgcn_mfma_f32_16x16x32_bf16(a, b, acc, 0, 0, 0);
        }
        const int c = wv * 16 + lr;
        float bc = attn_b[768 + c];
        float v[4];
        #pragma unroll
        for (int jj = 0; jj < 4; ++jj) {
            int row = n0 + qi * 4 + jj;
            v[jj] = acc[jj] + bc + x[(size_t)row * D + c];
        }
        ln_sb(v, redA, redB, lr, qi, wv, ln_g[c], ln_b[c]);
        #pragma unroll
        for (int jj = 0; jj < 4; ++jj) {
            sreg[jj] = v[jj];
            Sb[qi * 4 + jj][c] = f2b(v[jj]);
        }
    }
    __syncthreads();

    // ---- P5: Wq2 (Sb) -> T1b -> q2 regs ----
    float q2[4];
    {
        const unsigned short* Wq2T = wB + 4 * 65536;
        f32x4 acc = {};
        #pragma unroll
        for (int kk = 0; kk < 256; kk += 32) {
            short8 a = *(const short8*)&Sb[lr][qi * 8 + kk];
            short8 b = *(const short8*)(Wq2T + (size_t)(wv * 16 + lr) * 256 + qi * 8 + kk);
            acc = __builtin_amdgcn_mfma_f32_16x16x32_bf16(a, b, acc, 0, 0, 0);
        }
        const int c = wv * 16 + lr;
        float bc = pattn_b[c];
        #pragma unroll
        for (int jj = 0; jj < 4; ++jj)
            T1b[qi * 4 + jj][c] = f2b(acc[jj] + bc);
        __syncthreads();
        short4v qv = *(const short4v*)&T1b[m][lane * 4];
        #pragma unroll
        for (int j = 0; j < 4; ++j) q2[j] = b2f(qv[j]);
    }

    // ---- A2: scores + in-register softmax + PV (bufK=K2, bufV=V2) ----
    {
        float sc[L];
        #pragma unroll
        for (int l = 0; l < L; ++l) {
            int u = (l / 5) * 20 + m + (l % 5);
            short4v kv = *(const short4v*)&bufK[u][lane * 4];
            float p = q2[0] * b2f(kv[0]);
            #pragma unroll
            for (int j = 1; j < 4; ++j) p = fmaf(q2[j], b2f(kv[j]), p);
            p += __shfl_xor(p, 1); p += __shfl_xor(p, 2); p += __shfl_xor(p, 4);
            sc[l] = p * SCALE;
        }
        float mx = sc[0];
        #pragma unroll
        for (int l = 1; l < L; ++l) mx = fmaxf(mx, sc[l]);
        float sum = 0.0f;
        #pragma unroll
        for (int l = 0; l < L; ++l) { sc[l] = __expf(sc[l] - mx); sum += sc[l]; }
        float inv = 1.0f / sum;
        float o[4] = {0.f, 0.f, 0.f, 0.f};
        #pragma unroll
        for (int l = 0; l < L; ++l) {
            int u = (l / 5) * 20 + m + (l % 5);
            short4v v4 = *(const short4v*)&bufV[u][lane * 4];
            #pragma unroll
            for (int j = 0; j < 4; ++j) o[j] = fmaf(sc[l], b2f(v4[j]), o[j]);
        }
        unsigned short u8[4];
        #pragma unroll
        for (int j = 0; j < 4; ++j) u8[j] = f2b(o[j] * inv);
        *(uint2*)&T1b[m][lane * 4] = *(uint2*)u8;
    }
    __syncthreads();

    // ---- P8: Wo2 + bias + resid(sreg) + LN2 -> s2reg + Sb ----
    float s2reg[4];
    {
        const unsigned short* Wo2T = wB + 7 * 65536;
        f32x4 acc = {};
        #pragma unroll
        for (int kk = 0; kk < 256; kk += 32) {
            short8 a = *(const short8*)&T1b[lr][qi * 8 + kk];
            short8 b = *(const short8*)(Wo2T + (size_t)(wv * 16 + lr) * 256 + qi * 8 + kk);
            acc = __builtin_amdgcn_mfma_f32_16x16x32_bf16(a, b, acc, 0, 0, 0);
        }
        const int c = wv * 16 + lr;
        float bc = pattn_b[768 + c];
        float v[4];
        #pragma unroll
        for (int jj = 0; jj < 4; ++jj)
            v[jj] = acc[jj] + bc + sreg[jj];
        ln_sb(v, redA, redB, lr, qi, wv, ln_g[512 + c], ln_b[512 + c]);
        #pragma unroll
        for (int jj = 0; jj < 4; ++jj) {
            s2reg[jj] = v[jj];
            Sb[qi * 4 + jj][c] = f2b(v[jj]);
        }
    }
    __syncthreads();

    // ---- P9: FF1 (Sb = S2) -> Hb ----
    {
        const unsigned short* W1T = wB + 524288;
        f32x4 acc[2] = {};
        #pragma unroll
        for (int kk = 0; kk < 256; kk += 32) {
            short8 a = *(const short8*)&Sb[lr][qi * 8 + kk];
            #pragma unroll
            for (int nf = 0; nf < 2; ++nf) {
                short8 b = *(const short8*)(W1T + (size_t)(wv * 32 + nf * 16 + lr) * 256 + qi * 8 + kk);
                acc[nf] = __builtin_amdgcn_mfma_f32_16x16x32_bf16(a, b, acc[nf], 0, 0, 0);
            }
        }
        #pragma unroll
        for (int nf = 0; nf < 2; ++nf) {
            int c = wv * 32 + nf * 16 + lr;
            float bc = ff_b1[c];
            #pragma unroll
            for (int jj = 0; jj < 4; ++jj)
                Hb[qi * 4 + jj][c] = f2b(fmaxf(acc[nf][jj] + bc, 0.0f));
        }
    }
    __syncthreads();

    // ---- P10: FF2 (K=512) + resid(s2reg) + LN1 + mask -> out ----
    {
        const unsigned short* W2T = wB + 655360;
        f32x4 acc = {};
        #pragma unroll
        for (int kk = 0; kk < 512; kk += 32) {
            short8 a = *(const short8*)&Hb[lr][qi * 8 + kk];
            short8 b = *(const short8*)(W2T + (size_t)(wv * 16 + lr) * 512 + qi * 8 + kk);
            acc = __builtin_amdgcn_mfma_f32_16x16x32_bf16(a, b, acc, 0, 0, 0);
        }
        const int c = wv * 16 + lr;
        float bc = ff_b2[c];
        float v[4];
        #pragma unroll
        for (int jj = 0; jj < 4; ++jj)
            v[jj] = acc[jj] + bc + s2reg[jj];
        ln_sb(v, redA, redB, lr, qi, wv, ln_g[256 + c], ln_b[256 + c]);
        #pragma unroll
        for (int jj = 0; jj < 4; ++jj) {
            int row = n0 + qi * 4 + jj;
            bool a = act_at(active, row >> 6, row & 63);
            out[(size_t)row * D + c] = a ? v[jj] : 0.0f;
        }
        if (tid < 16) {
            int row = n0 + tid;
            out[(size_t)NND + row] = act_at(active, row >> 6, row & 63) ? 1.0f : 0.0f;
        }
    }
}

extern "C" void kernel_launch(void* const* d_in, const int* in_sizes, int n_in,
                              void* d_out, int out_size, void* d_ws, size_t ws_size,
                              hipStream_t stream) {
    const float* x       = (const float*)d_in[0];
    const float* memory  = (const float*)d_in[1];
    const int*   active  = (const int*)d_in[2];
    const float* attn_w  = (const float*)d_in[3];
    const float* attn_b  = (const float*)d_in[4];
    const float* pattn_w = (const float*)d_in[5];
    const float* pattn_b = (const float*)d_in[6];
    const float* ff_w1   = (const float*)d_in[7];
    const float* ff_b1   = (const float*)d_in[8];
    const float* ff_w2   = (const float*)d_in[9];
    const float* ff_b2   = (const float*)d_in[10];
    const float* ln_g    = (const float*)d_in[11];
    const float* ln_b    = (const float*)d_in[12];
    float* out = (float*)d_out;

    unsigned short* wsb = (unsigned short*)d_ws;
    unsigned short* xmB  = wsb;
    unsigned short* memB = wsb + (size_t)NND;
    unsigned short* wB   = wsb + 2 * (size_t)NND;               // 786432 shorts
    unsigned short* q1b  = wB + 786432;
    unsigned short* k1b  = q1b + (size_t)NND;
    unsigned short* v1b  = k1b + (size_t)NND;
    unsigned short* k2b  = v1b + (size_t)NND;                   // 4097 rows
    unsigned short* v2b  = k2b + (size_t)NND + 256;             // 4097 rows

    hipFuncSetAttribute(reinterpret_cast<const void*>(fused_kernel),
                        hipFuncAttributeMaxDynamicSharedMemorySize, SMEM_SZ);

    hipLaunchKernelGGL(prep_kernel, dim3(704), dim3(256), 0, stream,
                       x, memory, active, attn_w, pattn_w, ff_w1, ff_w2, pattn_b,
                       xmB, memB, wB, k2b + (size_t)NND, v2b + (size_t)NND);
    hipLaunchKernelGGL(proj_gemm, dim3(64, 8), dim3(256), 0, stream,
                       xmB, memB, wB, attn_b, pattn_b, q1b, k1b, v1b, k2b, v2b);
    hipLaunchKernelGGL(fused_kernel, dim3(256), dim3(1024), SMEM_SZ, stream,
                       active, x, wB, attn_b, pattn_b, ff_b1, ff_b2, ln_g, ln_b,
                       q1b, k1b, v1b, k2b, v2b, out);
}